// Round 7
// baseline (233.894 us; speedup 1.0000x reference)
//
#include <hip/hip_runtime.h>
#include <hip/hip_bf16.h>
#include <math.h>

#define BB 8
#define TT 256
#define DD 1024
#define HH 512
#define NSPANS 32896   // T*(T+1)/2
#define KK 512
#define NEGV -1e20f
#define NCH 32
#define CHSZ 1028      // NSPANS / NCH
#define NTILE 136      // 16*17/2 span tiles per batch

// ---------------------------------------------------------------------------
// Kernel 1: fused hs = X@Ws + bs ; he = X@We + be
// 64x64 C-tile, 512 threads = 2 K-groups. A staged in LDS (broadcast-cheap
// frag reads); B-frag read DIRECTLY from global/L2 (256B/wave, 4x lane dup,
// W is L2-resident) — halves LDS-pipe pressure vs R6.
// ---------------------------------------------------------------------------
__global__ __launch_bounds__(512) void gemm_proj(
    const float* __restrict__ X,
    const float* __restrict__ Ws, const float* __restrict__ bs,
    const float* __restrict__ We, const float* __restrict__ be,
    float* __restrict__ hs, float* __restrict__ he)
{
    const int bid = blockIdx.x;
    const int lg  = ((bid & 7) << 6) + (bid >> 3);   // XCD-chunked swizzle
    const int z   = lg >> 8;
    const int my  = (lg & 255) >> 3, nx = lg & 7;
    const int m0  = my * 64, n0 = nx * 64;

    const float* __restrict__ W    = z ? We : Ws;
    const float* __restrict__ bias = z ? be : bs;
    float*       __restrict__ Y    = z ? he : hs;

    __shared__ float As[2][32][68];   // [group][k][m]; also reused as red buf

    const int tid = threadIdx.x;
    const int grp = tid >> 8;
    const int t   = tid & 255;
    const int tx = t & 15, ty = t >> 4;

    const int kc4 = t & 7,  mr = t >> 3;   // A loader: 8 f4-cols x 32 rows
    const int kbase = grp * 512;

    const float4* X4 = (const float4*)X;
    const float4* W4 = (const float4*)W;

    float4 av0 = X4[((m0 + mr) * DD + kbase) / 4 + kc4];
    float4 av1 = X4[((m0 + mr + 32) * DD + kbase) / 4 + kc4];

    float acc[4][4] = {};

    for (int tkt = 0; tkt < 16; ++tkt) {
        {
            const float* a0 = (const float*)&av0;
            const float* a1 = (const float*)&av1;
            #pragma unroll
            for (int j = 0; j < 4; ++j) {
                As[grp][kc4*4 + j][mr]      = a0[j];
                As[grp][kc4*4 + j][mr + 32] = a1[j];
            }
        }
        __syncthreads();

        if (tkt < 15) {
            const int k0n = kbase + (tkt + 1) * 32;
            av0 = X4[((m0 + mr) * DD + k0n) / 4 + kc4];
            av1 = X4[((m0 + mr + 32) * DD + k0n) / 4 + kc4];
        }

        const int kt0 = kbase + tkt * 32;
        #pragma unroll 8
        for (int k = 0; k < 32; ++k) {
            const float4 a4 = *(const float4*)&As[grp][k][ty*4];
            const float4 b4 = W4[((kt0 + k) * HH + n0) / 4 + tx];  // L2 hit
            const float* a = (const float*)&a4;
            const float* b = (const float*)&b4;
            #pragma unroll
            for (int i = 0; i < 4; ++i)
                #pragma unroll
                for (int j = 0; j < 4; ++j)
                    acc[i][j] += a[i] * b[j];
        }
        __syncthreads();
    }

    // pair-reduce the two K-halves through LDS (As = 4352 floats >= 4096)
    float* red = &As[0][0][0];
    if (grp == 1) {
        #pragma unroll
        for (int i = 0; i < 4; ++i)
            *(float4*)&red[t*16 + i*4] =
                make_float4(acc[i][0], acc[i][1], acc[i][2], acc[i][3]);
    }
    __syncthreads();
    if (grp == 0) {
        const float4 bf = *(const float4*)&bias[n0 + tx*4];
        const float* bp = (const float*)&bf;
        #pragma unroll
        for (int i = 0; i < 4; ++i) {
            const float4 r = *(const float4*)&red[t*16 + i*4];
            const float* rp = (const float*)&r;
            const int m = m0 + ty*4 + i;
            float4 o;
            o.x = acc[i][0] + rp[0] + bp[0];
            o.y = acc[i][1] + rp[1] + bp[1];
            o.z = acc[i][2] + rp[2] + bp[2];
            o.w = acc[i][3] + rp[3] + bp[3];
            *(float4*)&Y[m * HH + n0 + tx*4] = o;
        }
    }
}

// ---------------------------------------------------------------------------
__device__ inline unsigned f2key(float f) {
    unsigned u = __float_as_uint(f);
    return u ^ ((u & 0x80000000u) ? 0xFFFFFFFFu : 0x80000000u);
}

// ---------------------------------------------------------------------------
// Kernel 2: span scores + fused LDS-aggregated 12-bit histogram.
// Hist is u16-packed (2 bins/word, counts <= 256) -> 8KB extra LDS; global
// merge emits only sparse aggregated atomics (tens per block). This is NOT
// the R5 failure mode (per-span un-aggregated global atomics).
// ---------------------------------------------------------------------------
__global__ __launch_bounds__(256) void span_scores(
    const float* __restrict__ hs, const float* __restrict__ he,
    const float* __restrict__ w_score, const float* __restrict__ b_score,
    const int* __restrict__ input_mask, float* __restrict__ scores,
    unsigned* __restrict__ hist12)
{
    const int bx = blockIdx.x;
    const int b = bx / NTILE;
    int tI = bx - b * NTILE;
    int i = 0, cum = 0;
    while (tI >= cum + (16 - i)) { cum += 16 - i; ++i; }
    const int j = i + (tI - cum);
    const int s0 = i * 16, e0 = j * 16;

    __shared__ float shs[16][516];
    __shared__ float she[16][516];
    __shared__ float sw[512];
    __shared__ unsigned lh[2048];    // 4096 bins packed as 2 x u16

    const int tid = threadIdx.x;
    const float4* hs4 = (const float4*)hs;
    const float4* he4 = (const float4*)he;

    for (int idx = tid; idx < 2048; idx += 256) lh[idx] = 0;

    for (int idx = tid; idx < 4096; idx += 256) {
        const int row = idx >> 7;
        const int c4  = idx & 127;
        if (row < 16) {
            *(float4*)&shs[row][c4*4] = hs4[((b*TT + s0 + row) * HH) / 4 + c4];
        } else {
            *(float4*)&she[row - 16][c4*4] = he4[((b*TT + e0 + row - 16) * HH) / 4 + c4];
        }
    }
    if (tid < 128) *(float4*)&sw[tid*4] = ((const float4*)w_score)[tid];
    __syncthreads();

    const int ii = tid >> 4, jj = tid & 15;
    const int s = s0 + ii, e = e0 + jj;

    float4 acc4 = make_float4(0.f, 0.f, 0.f, 0.f);
    #pragma unroll 4
    for (int c4 = 0; c4 < 128; ++c4) {
        const float4 a = *(const float4*)&shs[ii][c4*4];
        const float4 v = *(const float4*)&she[jj][c4*4];
        const float4 w = *(const float4*)&sw[c4*4];
        acc4.x += fmaxf(a.x + v.x, 0.f) * w.x;
        acc4.y += fmaxf(a.y + v.y, 0.f) * w.y;
        acc4.z += fmaxf(a.z + v.z, 0.f) * w.z;
        acc4.w += fmaxf(a.w + v.w, 0.f) * w.w;
    }

    if (e >= s) {
        float scv = (acc4.x + acc4.y) + (acc4.z + acc4.w) + b_score[0];
        if (!(input_mask[b*TT + s] && input_mask[b*TT + e])) scv = NEGV;
        scores[b*NSPANS + s*TT - (s*(s-1))/2 + (e - s)] = scv;
        const unsigned bin = f2key(scv) >> 20;
        atomicAdd(&lh[bin >> 1], 1u << ((bin & 1u) * 16));
    }
    __syncthreads();

    for (int idx = tid; idx < 2048; idx += 256) {
        const unsigned w = lh[idx];
        const unsigned lo = w & 0xFFFFu, hi = w >> 16;
        if (lo) atomicAdd(&hist12[b*4096 + 2*idx],     lo);
        if (hi) atomicAdd(&hist12[b*4096 + 2*idx + 1], hi);
    }
}

// ---------------------------------------------------------------------------
// 3b: find 12-bit prefix bin where cumulative-from-top crosses K
// ---------------------------------------------------------------------------
__global__ __launch_bounds__(1024) void find12(
    const unsigned* __restrict__ hist12, unsigned* __restrict__ thrInfo)
{
    const int b = blockIdx.x;
    const unsigned* h = hist12 + b*4096;
    const int tid = threadIdx.x;
    const int lane = tid & 63, wave = tid >> 6;

    const int hi = 4095 - tid*4;
    unsigned psum = h[hi] + h[hi-1] + h[hi-2] + h[hi-3];

    unsigned inc = psum;
    #pragma unroll
    for (int off = 1; off < 64; off <<= 1) {
        unsigned n = __shfl_up(inc, off);
        if (lane >= off) inc += n;
    }
    __shared__ unsigned wsum[16], wpre[16];
    if (lane == 63) wsum[wave] = inc;
    __syncthreads();
    if (tid == 0) { unsigned c = 0; for (int w = 0; w < 16; ++w) { wpre[w] = c; c += wsum[w]; } }
    __syncthreads();

    const unsigned before = wpre[wave] + inc - psum;
    if (before < KK && before + psum >= KK && psum > 0) {
        unsigned cum = before;
        int bin = hi;
        for (int jj = 0; jj < 4; ++jj) {
            const unsigned c = h[hi - jj];
            if (cum + c >= KK) { bin = hi - jj; break; }
            cum += c;
        }
        thrInfo[b*4 + 0] = (unsigned)bin;   // prefix12
        thrInfo[b*4 + 1] = KK - cum;        // remaining within bin
    }
}

// ---------------------------------------------------------------------------
// 3c: compact candidates (top-12 == prefix12), keep low 20 bits
// ---------------------------------------------------------------------------
__global__ __launch_bounds__(256) void compact_cand(
    const float* __restrict__ scores, const unsigned* __restrict__ thrInfo,
    unsigned* __restrict__ cand, unsigned* __restrict__ candCnt)
{
    const int b = blockIdx.x >> 5, ch = blockIdx.x & 31;
    const float* sc = scores + b*NSPANS;
    const unsigned p12 = thrInfo[b*4 + 0];
    const int base = ch*CHSZ;
    for (int i = base + threadIdx.x; i < base + CHSZ; i += 256) {
        const unsigned key = f2key(sc[i]);
        if ((key >> 20) == p12) {
            const unsigned pos = atomicAdd(&candCnt[b], 1u);
            cand[b*NSPANS + pos] = key & 0xFFFFFu;
        }
    }
}

// ---------------------------------------------------------------------------
// 3d: refine (two parallel 10-bit scan passes) + fused per-chunk counts and
// chunk-base prefix.
// ---------------------------------------------------------------------------
__global__ __launch_bounds__(1024) void refine(
    const unsigned* __restrict__ cand, const unsigned* __restrict__ candCnt,
    const float* __restrict__ scores,
    unsigned* __restrict__ thrInfo, unsigned* __restrict__ chunkBase)
{
    const int b = blockIdx.x;
    const unsigned* cd = cand + b*NSPANS;
    const unsigned n = candCnt[b];
    const unsigned remaining = thrInfo[b*4 + 1];
    const int tid = threadIdx.x;
    const int lane = tid & 63, wave = tid >> 6;

    __shared__ unsigned hist[1024];
    __shared__ unsigned wsum[16], wpre[16];
    __shared__ unsigned sh[2], shT[2];

    hist[tid] = 0;
    __syncthreads();
    for (unsigned i = tid; i < n; i += 1024) atomicAdd(&hist[(cd[i] >> 10) & 1023u], 1u);
    __syncthreads();
    {
        const unsigned psum = hist[1023 - tid];
        unsigned inc = psum;
        #pragma unroll
        for (int off = 1; off < 64; off <<= 1) {
            unsigned v = __shfl_up(inc, off);
            if (lane >= off) inc += v;
        }
        if (lane == 63) wsum[wave] = inc;
        __syncthreads();
        if (tid == 0) { unsigned c = 0; for (int w = 0; w < 16; ++w) { wpre[w] = c; c += wsum[w]; } }
        __syncthreads();
        const unsigned before = wpre[wave] + inc - psum;
        if (before < remaining && before + psum >= remaining && psum > 0) {
            sh[0] = 1023u - (unsigned)tid;
            sh[1] = remaining - before;
        }
        __syncthreads();
    }
    const unsigned b1 = sh[0], rem1 = sh[1];
    __syncthreads();

    hist[tid] = 0;
    __syncthreads();
    for (unsigned i = tid; i < n; i += 1024) {
        const unsigned v = cd[i];
        if (((v >> 10) & 1023u) == b1) atomicAdd(&hist[v & 1023u], 1u);
    }
    __syncthreads();
    {
        const unsigned psum = hist[1023 - tid];
        unsigned inc = psum;
        #pragma unroll
        for (int off = 1; off < 64; off <<= 1) {
            unsigned v = __shfl_up(inc, off);
            if (lane >= off) inc += v;
        }
        if (lane == 63) wsum[wave] = inc;
        __syncthreads();
        if (tid == 0) { unsigned c = 0; for (int w = 0; w < 16; ++w) { wpre[w] = c; c += wsum[w]; } }
        __syncthreads();
        const unsigned before = wpre[wave] + inc - psum;
        if (before < rem1 && before + psum >= rem1 && psum > 0) {
            const unsigned thrv = (thrInfo[b*4 + 0] << 20) | (b1 << 10) | (1023u - (unsigned)tid);
            thrInfo[b*4 + 2] = thrv;
            thrInfo[b*4 + 3] = rem1 - before;
            shT[0] = thrv;
            shT[1] = rem1 - before;
        }
    }
    __syncthreads();
    const unsigned thr = shT[0], ties = shT[1];

    __shared__ unsigned cg[NCH], ce[NCH];
    const float* sc = scores + b*NSPANS;
    #pragma unroll
    for (int q = 0; q < 2; ++q) {
        const int ch = wave*2 + q;
        const int base = ch*CHSZ, end = base + CHSZ;
        unsigned g = 0, e = 0;
        for (int i = base + lane; i < end; i += 64) {
            const unsigned key = f2key(sc[i]);
            g += (key > thr); e += (key == thr);
        }
        #pragma unroll
        for (int off = 32; off; off >>= 1) { g += __shfl_down(g, off); e += __shfl_down(e, off); }
        if (lane == 0) { cg[ch] = g; ce[ch] = e; }
    }
    __syncthreads();

    if (tid == 0) {
        unsigned out = 0, eqp = 0;
        for (int c = 0; c < NCH; ++c) {
            chunkBase[(b*NCH + c)*2 + 0] = out;
            chunkBase[(b*NCH + c)*2 + 1] = eqp;
            const unsigned room = (eqp >= ties) ? 0u : (ties - eqp);
            const unsigned taken = (ce[c] < room) ? ce[c] : room;
            out += cg[c] + taken;
            eqp += ce[c];
        }
    }
}

// ---------------------------------------------------------------------------
// 3f: stable ordered scatter; chunk bases precomputed by refine
// ---------------------------------------------------------------------------
__global__ __launch_bounds__(256) void scatter(
    const float* __restrict__ scores, const unsigned* __restrict__ thrInfo,
    const unsigned* __restrict__ chunkBase, int* __restrict__ top_idx)
{
    const int b = blockIdx.x >> 5, ch = blockIdx.x & 31;
    const float* sc = scores + b*NSPANS;
    const unsigned thr = thrInfo[b*4 + 2], ties = thrInfo[b*4 + 3];
    unsigned outPos = chunkBase[(b*NCH + ch)*2 + 0];
    unsigned eqPos  = chunkBase[(b*NCH + ch)*2 + 1];

    const int tid = threadIdx.x, wave = tid >> 6, lane = tid & 63;
    const unsigned long long lmask = (1ull << lane) - 1ull;
    __shared__ unsigned wS[4], wE[4];

    const int base = ch*CHSZ;
    for (int seg = base; seg < base + CHSZ; seg += 256) {
        const int i = seg + tid;
        const bool valid = (i < base + CHSZ);
        const unsigned key = valid ? f2key(sc[i]) : 0u;
        const bool g  = valid && key > thr;
        const bool eq = valid && key == thr;

        const unsigned long long meq = __ballot(eq);
        if (lane == 0) wE[wave] = (unsigned)__popcll(meq);
        __syncthreads();

        unsigned eqPre = eqPos;
        for (int w = 0; w < wave; ++w) eqPre += wE[w];
        const unsigned myEqRank = eqPre + (unsigned)__popcll(meq & lmask);
        const bool sel = g || (eq && myEqRank < ties);

        const unsigned long long msel = __ballot(sel);
        if (lane == 0) wS[wave] = (unsigned)__popcll(msel);
        __syncthreads();

        unsigned selPre = outPos;
        for (int w = 0; w < wave; ++w) selPre += wS[w];
        if (sel) top_idx[b*KK + selPre + (unsigned)__popcll(msel & lmask)] = i;

        unsigned totS = 0, totE = 0;
        #pragma unroll
        for (int w = 0; w < 4; ++w) { totS += wS[w]; totE += wE[w]; }
        __syncthreads();
        outPos += totS; eqPos += totE;
    }
}

// ---------------------------------------------------------------------------
// Kernel 4: finalize (probs + BCE loss), single block, deterministic
// ---------------------------------------------------------------------------
__global__ __launch_bounds__(1024) void finalize(
    const float* __restrict__ scores, const int* __restrict__ top_idx,
    const int* __restrict__ answer_spans, float* __restrict__ out)
{
    __shared__ int gold[BB*10];
    __shared__ float part[16];
    const int tid = threadIdx.x;

    if (tid < BB*10) {
        const int s0 = answer_spans[tid*2];
        const int e0 = answer_spans[tid*2 + 1];
        gold[tid] = (s0 >= 0) ? ((2*s0*TT - s0*s0 + s0)/2 + (e0 - s0)) : -1;
    }
    __syncthreads();

    float lsum = 0.f;
    for (int t = tid; t < BB*KK; t += 1024) {
        const int b = t >> 9;
        const int idx = top_idx[t];
        const float l = scores[b*NSPANS + idx];
        float prob = 0.f;
        if (l > -1e19f) {
            prob = 1.f / (1.f + expf(-l));
            float pred = 0.f;
            #pragma unroll
            for (int g = 0; g < 10; ++g)
                if (gold[b*10 + g] == idx) pred = 1.f;
            lsum += fmaxf(l, 0.f) - l*pred + log1pf(expf(-fabsf(l)));
        }
        out[t] = prob;
    }

    #pragma unroll
    for (int off = 32; off; off >>= 1) lsum += __shfl_down(lsum, off);
    const int wave = tid >> 6, lane = tid & 63;
    if (lane == 0) part[wave] = lsum;
    __syncthreads();
    if (tid == 0) {
        float ssum = 0.f;
        for (int w = 0; w < 16; ++w) ssum += part[w];
        out[BB*KK] = ssum;
    }
}

// ---------------------------------------------------------------------------
extern "C" void kernel_launch(void* const* d_in, const int* in_sizes, int n_in,
                              void* d_out, int out_size, void* d_ws, size_t ws_size,
                              hipStream_t stream)
{
    const float* inputs       = (const float*)d_in[0];
    const int*   input_mask   = (const int*)  d_in[1];
    const int*   answer_spans = (const int*)  d_in[2];
    const float* W_start      = (const float*)d_in[3];
    const float* b_start      = (const float*)d_in[4];
    const float* W_end        = (const float*)d_in[5];
    const float* b_end        = (const float*)d_in[6];
    const float* w_score      = (const float*)d_in[7];
    const float* b_score      = (const float*)d_in[8];
    float* out = (float*)d_out;
    unsigned* ws = (unsigned*)d_ws;

    float*    hs       = (float*)(ws);                 // 1048576 words
    float*    he       = (float*)(ws + 1048576);       // 1048576
    float*    scores   = (float*)(ws + 2097152);       // 263168
    int*      top_idx  = (int*)  (ws + 2360320);       // 4096
    unsigned* thrInfo  = ws + 2364416;                 // 32
    unsigned* chunkBase= ws + 2364448;                 // 512
    unsigned* hist12   = ws + 2364960;                 // 8*4096 = 32768
    unsigned* candCnt  = ws + 2397728;                 // 8 (contiguous after hist12)
    unsigned* cand     = (unsigned*)hs;                // alias, hs dead after span

    hipMemsetAsync(hist12, 0, (size_t)(BB*4096 + BB)*4, stream);  // hist12 + candCnt

    gemm_proj<<<512, 512, 0, stream>>>(inputs, W_start, b_start, W_end, b_end, hs, he);
    span_scores<<<BB*NTILE, 256, 0, stream>>>(hs, he, w_score, b_score, input_mask,
                                              scores, hist12);

    find12      <<<BB, 1024, 0, stream>>>(hist12, thrInfo);
    compact_cand<<<BB*NCH, 256, 0, stream>>>(scores, thrInfo, cand, candCnt);
    refine      <<<BB, 1024, 0, stream>>>(cand, candCnt, scores, thrInfo, chunkBase);
    scatter     <<<BB*NCH, 256, 0, stream>>>(scores, thrInfo, chunkBase, top_idx);

    finalize<<<1, 1024, 0, stream>>>(scores, top_idx, answer_spans, out);
}

// Round 8
// 139.213 us; speedup vs baseline: 1.6801x; 1.6801x over previous
//
#include <hip/hip_runtime.h>
#include <hip/hip_bf16.h>
#include <math.h>

#define BB 8
#define TT 256
#define DD 1024
#define HH 512
#define NSPANS 32896   // T*(T+1)/2
#define KK 512
#define NEGV -1e20f
#define NCH 32
#define CHSZ 1028      // NSPANS / NCH
#define NTILE 136      // 16*17/2 span tiles per batch

typedef __attribute__((ext_vector_type(8))) short bf16x8;
typedef __attribute__((ext_vector_type(4))) float f32x4;

__device__ inline unsigned short f2bf(float f) {          // RNE f32->bf16
    unsigned u = __float_as_uint(f);
    return (unsigned short)((u + 0x7FFFu + ((u >> 16) & 1u)) >> 16);
}
__device__ inline float bf2f(unsigned short u) {
    return __uint_as_float(((unsigned)u) << 16);
}
__device__ inline void split3(float v, unsigned short& a, unsigned short& b,
                              unsigned short& c) {
    a = f2bf(v);           float r  = v - bf2f(a);
    b = f2bf(r);           float r2 = r - bf2f(b);
    c = f2bf(r2);
}

// ---------------------------------------------------------------------------
// cvt_x: X [2048][1024] f32 -> xs0/1/2 bf16 (same layout). 4 elems/thread.
// ---------------------------------------------------------------------------
__global__ __launch_bounds__(256) void cvt_x(
    const float* __restrict__ X, unsigned short* __restrict__ x0,
    unsigned short* __restrict__ x1, unsigned short* __restrict__ x2)
{
    const int i4 = blockIdx.x * 256 + threadIdx.x;     // float4 index
    const float4 v = ((const float4*)X)[i4];
    const float vv[4] = {v.x, v.y, v.z, v.w};
    ushort4 h0, h1, h2;
    unsigned short* p0 = (unsigned short*)&h0;
    unsigned short* p1 = (unsigned short*)&h1;
    unsigned short* p2 = (unsigned short*)&h2;
    #pragma unroll
    for (int j = 0; j < 4; ++j) split3(vv[j], p0[j], p1[j], p2[j]);
    ((ushort4*)x0)[i4] = h0;
    ((ushort4*)x1)[i4] = h1;
    ((ushort4*)x2)[i4] = h2;
}

// ---------------------------------------------------------------------------
// cvt_w: Ws/We [1024][512] f32 -> wt [2][3][512][1024] bf16, TRANSPOSED.
// ---------------------------------------------------------------------------
__global__ __launch_bounds__(256) void cvt_w(
    const float* __restrict__ Ws, const float* __restrict__ We,
    unsigned short* __restrict__ wt)
{
    const int idx = blockIdx.x * 256 + threadIdx.x;    // 0 .. 2*524288
    const int z = idx >> 19;
    const int p = idx & 524287;                        // h*1024 + d
    const int h = p >> 10, d = p & 1023;
    const float v = (z ? We : Ws)[d * HH + h];
    unsigned short a, b, c;
    split3(v, a, b, c);
    unsigned short* base = wt + (size_t)z * 3 * 524288;
    base[0 * 524288 + p] = a;
    base[1 * 524288 + p] = b;
    base[2 * 524288 + p] = c;
}

// ---------------------------------------------------------------------------
// gemm_mfma: hs = X@Ws + bs ; he = X@We + be via bf16x3 split, 6 products.
// 64x64 C-tile, 4 waves x (32x32), K-tile 64, mfma_f32_16x16x32_bf16.
// ---------------------------------------------------------------------------
__global__ __launch_bounds__(256) void gemm_mfma(
    const unsigned short* __restrict__ xs,   // [3][2048][1024]
    const unsigned short* __restrict__ wt,   // [2][3][512][1024] (n-major)
    const float* __restrict__ bs, const float* __restrict__ be,
    float* __restrict__ hs, float* __restrict__ he)
{
    const int bid = blockIdx.x;
    const int lg  = ((bid & 7) << 6) + (bid >> 3);   // XCD-chunked swizzle
    const int z   = lg >> 8;
    const int my  = (lg & 255) >> 3, nx = lg & 7;
    const int m0 = my * 64, n0 = nx * 64;

    const unsigned short* __restrict__ W = wt + (size_t)z * 3 * 524288;
    const float* __restrict__ bias = z ? be : bs;
    float* __restrict__ Y = z ? he : hs;

    __shared__ __align__(16) unsigned short la[3][64][72];
    __shared__ __align__(16) unsigned short lb[3][64][72];

    const int tid = threadIdx.x;
    const int wave = tid >> 6, lane = tid & 63;
    const int wm = (wave >> 1) * 32, wn = (wave & 1) * 32;

    f32x4 acc[2][2];
    #pragma unroll
    for (int i = 0; i < 2; ++i)
        #pragma unroll
        for (int j = 0; j < 2; ++j) acc[i][j] = (f32x4){0.f, 0.f, 0.f, 0.f};

    const int rA = lane & 15;          // frag row/col within 16
    const int kq = lane >> 4;          // k-quarter

    for (int kt = 0; kt < 16; ++kt) {
        const int k0 = kt * 64;
        __syncthreads();               // prev compute done reading LDS
        #pragma unroll
        for (int sp = 0; sp < 3; ++sp) {
            #pragma unroll
            for (int it = 0; it < 2; ++it) {
                const int idx = it * 256 + tid;        // 0..511
                const int row = idx >> 3, c8 = idx & 7;
                *(int4*)&la[sp][row][c8 * 8] =
                    *(const int4*)&xs[(size_t)sp * 2097152 + (m0 + row) * 1024 + k0 + c8 * 8];
                *(int4*)&lb[sp][row][c8 * 8] =
                    *(const int4*)&W[(size_t)sp * 524288 + (n0 + row) * 1024 + k0 + c8 * 8];
            }
        }
        __syncthreads();

        #pragma unroll
        for (int s = 0; s < 2; ++s) {
            const int kl = s * 32 + kq * 8;
            bf16x8 af[3][2], bg[3][2];
            #pragma unroll
            for (int sp = 0; sp < 3; ++sp) {
                #pragma unroll
                for (int f = 0; f < 2; ++f) {
                    af[sp][f] = *(const bf16x8*)&la[sp][wm + f * 16 + rA][kl];
                    bg[sp][f] = *(const bf16x8*)&lb[sp][wn + f * 16 + rA][kl];
                }
            }
            #pragma unroll
            for (int fm = 0; fm < 2; ++fm)
                #pragma unroll
                for (int fn = 0; fn < 2; ++fn) {
                    // products (i,j), i+j<=2: 00, 01, 10, 11, 02, 20
                    acc[fm][fn] = __builtin_amdgcn_mfma_f32_16x16x32_bf16(
                        af[0][fm], bg[0][fn], acc[fm][fn], 0, 0, 0);
                    acc[fm][fn] = __builtin_amdgcn_mfma_f32_16x16x32_bf16(
                        af[0][fm], bg[1][fn], acc[fm][fn], 0, 0, 0);
                    acc[fm][fn] = __builtin_amdgcn_mfma_f32_16x16x32_bf16(
                        af[1][fm], bg[0][fn], acc[fm][fn], 0, 0, 0);
                    acc[fm][fn] = __builtin_amdgcn_mfma_f32_16x16x32_bf16(
                        af[1][fm], bg[1][fn], acc[fm][fn], 0, 0, 0);
                    acc[fm][fn] = __builtin_amdgcn_mfma_f32_16x16x32_bf16(
                        af[0][fm], bg[2][fn], acc[fm][fn], 0, 0, 0);
                    acc[fm][fn] = __builtin_amdgcn_mfma_f32_16x16x32_bf16(
                        af[2][fm], bg[0][fn], acc[fm][fn], 0, 0, 0);
                }
        }
    }

    // epilogue: D row=(lane>>4)*4+reg, col=lane&15 (m89-verified mapping)
    const int col = lane & 15, rq = lane >> 4;
    #pragma unroll
    for (int fm = 0; fm < 2; ++fm)
        #pragma unroll
        for (int fn = 0; fn < 2; ++fn) {
            const int nn = n0 + wn + fn * 16 + col;
            const float bv = bias[nn];
            #pragma unroll
            for (int r = 0; r < 4; ++r) {
                const int mm = m0 + wm + fm * 16 + rq * 4 + r;
                Y[mm * HH + nn] = acc[fm][fn][r] + bv;
            }
        }
}

// ---------------------------------------------------------------------------
__device__ inline unsigned f2key(float f) {
    unsigned u = __float_as_uint(f);
    return u ^ ((u & 0x80000000u) ? 0xFFFFFFFFu : 0x80000000u);
}

// ---------------------------------------------------------------------------
// span_scores + fused LDS-aggregated 12-bit histogram (verified R7, absmax 0)
// ---------------------------------------------------------------------------
__global__ __launch_bounds__(256) void span_scores(
    const float* __restrict__ hs, const float* __restrict__ he,
    const float* __restrict__ w_score, const float* __restrict__ b_score,
    const int* __restrict__ input_mask, float* __restrict__ scores,
    unsigned* __restrict__ hist12)
{
    const int bx = blockIdx.x;
    const int b = bx / NTILE;
    int tI = bx - b * NTILE;
    int i = 0, cum = 0;
    while (tI >= cum + (16 - i)) { cum += 16 - i; ++i; }
    const int j = i + (tI - cum);
    const int s0 = i * 16, e0 = j * 16;

    __shared__ float shs[16][516];
    __shared__ float she[16][516];
    __shared__ float sw[512];
    __shared__ unsigned lh[2048];

    const int tid = threadIdx.x;
    const float4* hs4 = (const float4*)hs;
    const float4* he4 = (const float4*)he;

    for (int idx = tid; idx < 2048; idx += 256) lh[idx] = 0;

    for (int idx = tid; idx < 4096; idx += 256) {
        const int row = idx >> 7;
        const int c4  = idx & 127;
        if (row < 16) {
            *(float4*)&shs[row][c4*4] = hs4[((b*TT + s0 + row) * HH) / 4 + c4];
        } else {
            *(float4*)&she[row - 16][c4*4] = he4[((b*TT + e0 + row - 16) * HH) / 4 + c4];
        }
    }
    if (tid < 128) *(float4*)&sw[tid*4] = ((const float4*)w_score)[tid];
    __syncthreads();

    const int ii = tid >> 4, jj = tid & 15;
    const int s = s0 + ii, e = e0 + jj;

    float4 acc4 = make_float4(0.f, 0.f, 0.f, 0.f);
    #pragma unroll 4
    for (int c4 = 0; c4 < 128; ++c4) {
        const float4 a = *(const float4*)&shs[ii][c4*4];
        const float4 v = *(const float4*)&she[jj][c4*4];
        const float4 w = *(const float4*)&sw[c4*4];
        acc4.x += fmaxf(a.x + v.x, 0.f) * w.x;
        acc4.y += fmaxf(a.y + v.y, 0.f) * w.y;
        acc4.z += fmaxf(a.z + v.z, 0.f) * w.z;
        acc4.w += fmaxf(a.w + v.w, 0.f) * w.w;
    }

    if (e >= s) {
        float scv = (acc4.x + acc4.y) + (acc4.z + acc4.w) + b_score[0];
        if (!(input_mask[b*TT + s] && input_mask[b*TT + e])) scv = NEGV;
        scores[b*NSPANS + s*TT - (s*(s-1))/2 + (e - s)] = scv;
        const unsigned bin = f2key(scv) >> 20;
        atomicAdd(&lh[bin >> 1], 1u << ((bin & 1u) * 16));
    }
    __syncthreads();

    for (int idx = tid; idx < 2048; idx += 256) {
        const unsigned w = lh[idx];
        const unsigned lo = w & 0xFFFFu, hi = w >> 16;
        if (lo) atomicAdd(&hist12[b*4096 + 2*idx],     lo);
        if (hi) atomicAdd(&hist12[b*4096 + 2*idx + 1], hi);
    }
}

// ---------------------------------------------------------------------------
__global__ __launch_bounds__(1024) void find12(
    const unsigned* __restrict__ hist12, unsigned* __restrict__ thrInfo)
{
    const int b = blockIdx.x;
    const unsigned* h = hist12 + b*4096;
    const int tid = threadIdx.x;
    const int lane = tid & 63, wave = tid >> 6;

    const int hi = 4095 - tid*4;
    unsigned psum = h[hi] + h[hi-1] + h[hi-2] + h[hi-3];

    unsigned inc = psum;
    #pragma unroll
    for (int off = 1; off < 64; off <<= 1) {
        unsigned n = __shfl_up(inc, off);
        if (lane >= off) inc += n;
    }
    __shared__ unsigned wsum[16], wpre[16];
    if (lane == 63) wsum[wave] = inc;
    __syncthreads();
    if (tid == 0) { unsigned c = 0; for (int w = 0; w < 16; ++w) { wpre[w] = c; c += wsum[w]; } }
    __syncthreads();

    const unsigned before = wpre[wave] + inc - psum;
    if (before < KK && before + psum >= KK && psum > 0) {
        unsigned cum = before;
        int bin = hi;
        for (int jj = 0; jj < 4; ++jj) {
            const unsigned c = h[hi - jj];
            if (cum + c >= KK) { bin = hi - jj; break; }
            cum += c;
        }
        thrInfo[b*4 + 0] = (unsigned)bin;
        thrInfo[b*4 + 1] = KK - cum;
    }
}

// ---------------------------------------------------------------------------
__global__ __launch_bounds__(256) void compact_cand(
    const float* __restrict__ scores, const unsigned* __restrict__ thrInfo,
    unsigned* __restrict__ cand, unsigned* __restrict__ candCnt)
{
    const int b = blockIdx.x >> 5, ch = blockIdx.x & 31;
    const float* sc = scores + b*NSPANS;
    const unsigned p12 = thrInfo[b*4 + 0];
    const int base = ch*CHSZ;
    for (int i = base + threadIdx.x; i < base + CHSZ; i += 256) {
        const unsigned key = f2key(sc[i]);
        if ((key >> 20) == p12) {
            const unsigned pos = atomicAdd(&candCnt[b], 1u);
            cand[b*NSPANS + pos] = key & 0xFFFFFu;
        }
    }
}

// ---------------------------------------------------------------------------
__global__ __launch_bounds__(1024) void refine(
    const unsigned* __restrict__ cand, const unsigned* __restrict__ candCnt,
    const float* __restrict__ scores,
    unsigned* __restrict__ thrInfo, unsigned* __restrict__ chunkBase)
{
    const int b = blockIdx.x;
    const unsigned* cd = cand + b*NSPANS;
    const unsigned n = candCnt[b];
    const unsigned remaining = thrInfo[b*4 + 1];
    const int tid = threadIdx.x;
    const int lane = tid & 63, wave = tid >> 6;

    __shared__ unsigned hist[1024];
    __shared__ unsigned wsum[16], wpre[16];
    __shared__ unsigned sh[2], shT[2];

    hist[tid] = 0;
    __syncthreads();
    for (unsigned i = tid; i < n; i += 1024) atomicAdd(&hist[(cd[i] >> 10) & 1023u], 1u);
    __syncthreads();
    {
        const unsigned psum = hist[1023 - tid];
        unsigned inc = psum;
        #pragma unroll
        for (int off = 1; off < 64; off <<= 1) {
            unsigned v = __shfl_up(inc, off);
            if (lane >= off) inc += v;
        }
        if (lane == 63) wsum[wave] = inc;
        __syncthreads();
        if (tid == 0) { unsigned c = 0; for (int w = 0; w < 16; ++w) { wpre[w] = c; c += wsum[w]; } }
        __syncthreads();
        const unsigned before = wpre[wave] + inc - psum;
        if (before < remaining && before + psum >= remaining && psum > 0) {
            sh[0] = 1023u - (unsigned)tid;
            sh[1] = remaining - before;
        }
        __syncthreads();
    }
    const unsigned b1 = sh[0], rem1 = sh[1];
    __syncthreads();

    hist[tid] = 0;
    __syncthreads();
    for (unsigned i = tid; i < n; i += 1024) {
        const unsigned v = cd[i];
        if (((v >> 10) & 1023u) == b1) atomicAdd(&hist[v & 1023u], 1u);
    }
    __syncthreads();
    {
        const unsigned psum = hist[1023 - tid];
        unsigned inc = psum;
        #pragma unroll
        for (int off = 1; off < 64; off <<= 1) {
            unsigned v = __shfl_up(inc, off);
            if (lane >= off) inc += v;
        }
        if (lane == 63) wsum[wave] = inc;
        __syncthreads();
        if (tid == 0) { unsigned c = 0; for (int w = 0; w < 16; ++w) { wpre[w] = c; c += wsum[w]; } }
        __syncthreads();
        const unsigned before = wpre[wave] + inc - psum;
        if (before < rem1 && before + psum >= rem1 && psum > 0) {
            const unsigned thrv = (thrInfo[b*4 + 0] << 20) | (b1 << 10) | (1023u - (unsigned)tid);
            thrInfo[b*4 + 2] = thrv;
            thrInfo[b*4 + 3] = rem1 - before;
            shT[0] = thrv;
            shT[1] = rem1 - before;
        }
    }
    __syncthreads();
    const unsigned thr = shT[0], ties = shT[1];

    __shared__ unsigned cg[NCH], ce[NCH];
    const float* sc = scores + b*NSPANS;
    #pragma unroll
    for (int q = 0; q < 2; ++q) {
        const int ch = wave*2 + q;
        const int base = ch*CHSZ, end = base + CHSZ;
        unsigned g = 0, e = 0;
        for (int i = base + lane; i < end; i += 64) {
            const unsigned key = f2key(sc[i]);
            g += (key > thr); e += (key == thr);
        }
        #pragma unroll
        for (int off = 32; off; off >>= 1) { g += __shfl_down(g, off); e += __shfl_down(e, off); }
        if (lane == 0) { cg[ch] = g; ce[ch] = e; }
    }
    __syncthreads();

    if (tid == 0) {
        unsigned out = 0, eqp = 0;
        for (int c = 0; c < NCH; ++c) {
            chunkBase[(b*NCH + c)*2 + 0] = out;
            chunkBase[(b*NCH + c)*2 + 1] = eqp;
            const unsigned room = (eqp >= ties) ? 0u : (ties - eqp);
            const unsigned taken = (ce[c] < room) ? ce[c] : room;
            out += cg[c] + taken;
            eqp += ce[c];
        }
    }
}

// ---------------------------------------------------------------------------
__global__ __launch_bounds__(256) void scatter(
    const float* __restrict__ scores, const unsigned* __restrict__ thrInfo,
    const unsigned* __restrict__ chunkBase, int* __restrict__ top_idx)
{
    const int b = blockIdx.x >> 5, ch = blockIdx.x & 31;
    const float* sc = scores + b*NSPANS;
    const unsigned thr = thrInfo[b*4 + 2], ties = thrInfo[b*4 + 3];
    unsigned outPos = chunkBase[(b*NCH + ch)*2 + 0];
    unsigned eqPos  = chunkBase[(b*NCH + ch)*2 + 1];

    const int tid = threadIdx.x, wave = tid >> 6, lane = tid & 63;
    const unsigned long long lmask = (1ull << lane) - 1ull;
    __shared__ unsigned wS[4], wE[4];

    const int base = ch*CHSZ;
    for (int seg = base; seg < base + CHSZ; seg += 256) {
        const int i = seg + tid;
        const bool valid = (i < base + CHSZ);
        const unsigned key = valid ? f2key(sc[i]) : 0u;
        const bool g  = valid && key > thr;
        const bool eq = valid && key == thr;

        const unsigned long long meq = __ballot(eq);
        if (lane == 0) wE[wave] = (unsigned)__popcll(meq);
        __syncthreads();

        unsigned eqPre = eqPos;
        for (int w = 0; w < wave; ++w) eqPre += wE[w];
        const unsigned myEqRank = eqPre + (unsigned)__popcll(meq & lmask);
        const bool sel = g || (eq && myEqRank < ties);

        const unsigned long long msel = __ballot(sel);
        if (lane == 0) wS[wave] = (unsigned)__popcll(msel);
        __syncthreads();

        unsigned selPre = outPos;
        for (int w = 0; w < wave; ++w) selPre += wS[w];
        if (sel) top_idx[b*KK + selPre + (unsigned)__popcll(msel & lmask)] = i;

        unsigned totS = 0, totE = 0;
        #pragma unroll
        for (int w = 0; w < 4; ++w) { totS += wS[w]; totE += wE[w]; }
        __syncthreads();
        outPos += totS; eqPos += totE;
    }
}

// ---------------------------------------------------------------------------
__global__ __launch_bounds__(1024) void finalize(
    const float* __restrict__ scores, const int* __restrict__ top_idx,
    const int* __restrict__ answer_spans, float* __restrict__ out)
{
    __shared__ int gold[BB*10];
    __shared__ float part[16];
    const int tid = threadIdx.x;

    if (tid < BB*10) {
        const int s0 = answer_spans[tid*2];
        const int e0 = answer_spans[tid*2 + 1];
        gold[tid] = (s0 >= 0) ? ((2*s0*TT - s0*s0 + s0)/2 + (e0 - s0)) : -1;
    }
    __syncthreads();

    float lsum = 0.f;
    for (int t = tid; t < BB*KK; t += 1024) {
        const int b = t >> 9;
        const int idx = top_idx[t];
        const float l = scores[b*NSPANS + idx];
        float prob = 0.f;
        if (l > -1e19f) {
            prob = 1.f / (1.f + expf(-l));
            float pred = 0.f;
            #pragma unroll
            for (int g = 0; g < 10; ++g)
                if (gold[b*10 + g] == idx) pred = 1.f;
            lsum += fmaxf(l, 0.f) - l*pred + log1pf(expf(-fabsf(l)));
        }
        out[t] = prob;
    }

    #pragma unroll
    for (int off = 32; off; off >>= 1) lsum += __shfl_down(lsum, off);
    const int wave = tid >> 6, lane = tid & 63;
    if (lane == 0) part[wave] = lsum;
    __syncthreads();
    if (tid == 0) {
        float ssum = 0.f;
        for (int w = 0; w < 16; ++w) ssum += part[w];
        out[BB*KK] = ssum;
    }
}

// ---------------------------------------------------------------------------
extern "C" void kernel_launch(void* const* d_in, const int* in_sizes, int n_in,
                              void* d_out, int out_size, void* d_ws, size_t ws_size,
                              hipStream_t stream)
{
    const float* inputs       = (const float*)d_in[0];
    const int*   input_mask   = (const int*)  d_in[1];
    const int*   answer_spans = (const int*)  d_in[2];
    const float* W_start      = (const float*)d_in[3];
    const float* b_start      = (const float*)d_in[4];
    const float* W_end        = (const float*)d_in[5];
    const float* b_end        = (const float*)d_in[6];
    const float* w_score      = (const float*)d_in[7];
    const float* b_score      = (const float*)d_in[8];
    float* out = (float*)d_out;
    unsigned* ws = (unsigned*)d_ws;

    // word-offset layout
    float*    hs       = (float*)(ws);                 // 1048576
    float*    he       = (float*)(ws + 1048576);       // 1048576
    float*    scores   = (float*)(ws + 2097152);       // 263168
    int*      top_idx  = (int*)  (ws + 2360320);       // 4096
    unsigned* thrInfo  = ws + 2364416;                 // 32
    unsigned* chunkBase= ws + 2364448;                 // 512
    unsigned* hist12   = ws + 2364960;                 // 32768
    unsigned* candCnt  = ws + 2397728;                 // 8 (contiguous w/ hist12)
    unsigned short* xs = (unsigned short*)(ws + 2397736);   // 3*2097152 bf16
    unsigned short* wt = (unsigned short*)(ws + 5543464);   // 2*3*524288 bf16
    unsigned* cand     = (unsigned*)hs;                // alias, hs dead after span

    hipMemsetAsync(hist12, 0, (size_t)(BB*4096 + BB)*4, stream);  // hist12+candCnt

    cvt_x<<<2048, 256, 0, stream>>>(inputs, xs, xs + 2097152, xs + 4194304);
    cvt_w<<<4096, 256, 0, stream>>>(W_start, W_end, wt);
    gemm_mfma<<<512, 256, 0, stream>>>(xs, wt, b_start, b_end, hs, he);

    span_scores<<<BB*NTILE, 256, 0, stream>>>(hs, he, w_score, b_score, input_mask,
                                              scores, hist12);

    find12      <<<BB, 1024, 0, stream>>>(hist12, thrInfo);
    compact_cand<<<BB*NCH, 256, 0, stream>>>(scores, thrInfo, cand, candCnt);
    refine      <<<BB, 1024, 0, stream>>>(cand, candCnt, scores, thrInfo, chunkBase);
    scatter     <<<BB*NCH, 256, 0, stream>>>(scores, thrInfo, chunkBase, top_idx);

    finalize<<<1, 1024, 0, stream>>>(scores, top_idx, answer_spans, out);
}

// Round 9
// 123.414 us; speedup vs baseline: 1.8952x; 1.1280x over previous
//
#include <hip/hip_runtime.h>
#include <hip/hip_bf16.h>
#include <math.h>

#define BB 8
#define TT 256
#define DD 1024
#define HH 512
#define NSPANS 32896   // T*(T+1)/2
#define KK 512
#define NEGV -1e20f
#define NCH 32
#define CHSZ 1028      // NSPANS / NCH
#define NT32 36        // 8*9/2 span tiles (32x32) per batch

typedef __attribute__((ext_vector_type(8))) short bf16x8;
typedef __attribute__((ext_vector_type(4))) float f32x4;

__device__ inline unsigned short f2bf(float f) {          // RNE f32->bf16
    unsigned u = __float_as_uint(f);
    return (unsigned short)((u + 0x7FFFu + ((u >> 16) & 1u)) >> 16);
}
__device__ inline float bf2f(unsigned short u) {
    return __uint_as_float(((unsigned)u) << 16);
}
__device__ inline void split3(float v, unsigned short& a, unsigned short& b,
                              unsigned short& c) {
    a = f2bf(v);           float r  = v - bf2f(a);
    b = f2bf(r);           float r2 = r - bf2f(b);
    c = f2bf(r2);
}

// ---------------------------------------------------------------------------
// cvt_x: X [2048][1024] f32 -> xs0/1/2 bf16 (same layout). 4 elems/thread.
// ---------------------------------------------------------------------------
__global__ __launch_bounds__(256) void cvt_x(
    const float* __restrict__ X, unsigned short* __restrict__ x0,
    unsigned short* __restrict__ x1, unsigned short* __restrict__ x2)
{
    const int i4 = blockIdx.x * 256 + threadIdx.x;     // float4 index
    const float4 v = ((const float4*)X)[i4];
    const float vv[4] = {v.x, v.y, v.z, v.w};
    ushort4 h0, h1, h2;
    unsigned short* p0 = (unsigned short*)&h0;
    unsigned short* p1 = (unsigned short*)&h1;
    unsigned short* p2 = (unsigned short*)&h2;
    #pragma unroll
    for (int j = 0; j < 4; ++j) split3(vv[j], p0[j], p1[j], p2[j]);
    ((ushort4*)x0)[i4] = h0;
    ((ushort4*)x1)[i4] = h1;
    ((ushort4*)x2)[i4] = h2;
}

// ---------------------------------------------------------------------------
// cvt_w: Ws/We [1024][512] f32 -> wt [2][3][512][1024] bf16, TRANSPOSED.
// ---------------------------------------------------------------------------
__global__ __launch_bounds__(256) void cvt_w(
    const float* __restrict__ Ws, const float* __restrict__ We,
    unsigned short* __restrict__ wt)
{
    const int idx = blockIdx.x * 256 + threadIdx.x;    // 0 .. 2*524288
    const int z = idx >> 19;
    const int p = idx & 524287;                        // h*1024 + d
    const int h = p >> 10, d = p & 1023;
    const float v = (z ? We : Ws)[d * HH + h];
    unsigned short a, b, c;
    split3(v, a, b, c);
    unsigned short* base = wt + (size_t)z * 3 * 524288;
    base[0 * 524288 + p] = a;
    base[1 * 524288 + p] = b;
    base[2 * 524288 + p] = c;
}

// ---------------------------------------------------------------------------
// gemm_mfma: hs = X@Ws + bs ; he = X@We + be via bf16x3 split, 6 products.
// 64x64 C-tile, 4 waves x (32x32), K-tile 64, mfma_f32_16x16x32_bf16.
// ---------------------------------------------------------------------------
__global__ __launch_bounds__(256) void gemm_mfma(
    const unsigned short* __restrict__ xs,   // [3][2048][1024]
    const unsigned short* __restrict__ wt,   // [2][3][512][1024] (n-major)
    const float* __restrict__ bs, const float* __restrict__ be,
    float* __restrict__ hs, float* __restrict__ he)
{
    const int bid = blockIdx.x;
    const int lg  = ((bid & 7) << 6) + (bid >> 3);   // XCD-chunked swizzle
    const int z   = lg >> 8;
    const int my  = (lg & 255) >> 3, nx = lg & 7;
    const int m0 = my * 64, n0 = nx * 64;

    const unsigned short* __restrict__ W = wt + (size_t)z * 3 * 524288;
    const float* __restrict__ bias = z ? be : bs;
    float* __restrict__ Y = z ? he : hs;

    __shared__ __align__(16) unsigned short la[3][64][72];
    __shared__ __align__(16) unsigned short lb[3][64][72];

    const int tid = threadIdx.x;
    const int wave = tid >> 6, lane = tid & 63;
    const int wm = (wave >> 1) * 32, wn = (wave & 1) * 32;

    f32x4 acc[2][2];
    #pragma unroll
    for (int i = 0; i < 2; ++i)
        #pragma unroll
        for (int j = 0; j < 2; ++j) acc[i][j] = (f32x4){0.f, 0.f, 0.f, 0.f};

    const int rA = lane & 15;
    const int kq = lane >> 4;

    for (int kt = 0; kt < 16; ++kt) {
        const int k0 = kt * 64;
        __syncthreads();
        #pragma unroll
        for (int sp = 0; sp < 3; ++sp) {
            #pragma unroll
            for (int it = 0; it < 2; ++it) {
                const int idx = it * 256 + tid;
                const int row = idx >> 3, c8 = idx & 7;
                *(int4*)&la[sp][row][c8 * 8] =
                    *(const int4*)&xs[(size_t)sp * 2097152 + (m0 + row) * 1024 + k0 + c8 * 8];
                *(int4*)&lb[sp][row][c8 * 8] =
                    *(const int4*)&W[(size_t)sp * 524288 + (n0 + row) * 1024 + k0 + c8 * 8];
            }
        }
        __syncthreads();

        #pragma unroll
        for (int s = 0; s < 2; ++s) {
            const int kl = s * 32 + kq * 8;
            bf16x8 af[3][2], bg[3][2];
            #pragma unroll
            for (int sp = 0; sp < 3; ++sp) {
                #pragma unroll
                for (int f = 0; f < 2; ++f) {
                    af[sp][f] = *(const bf16x8*)&la[sp][wm + f * 16 + rA][kl];
                    bg[sp][f] = *(const bf16x8*)&lb[sp][wn + f * 16 + rA][kl];
                }
            }
            #pragma unroll
            for (int fm = 0; fm < 2; ++fm)
                #pragma unroll
                for (int fn = 0; fn < 2; ++fn) {
                    acc[fm][fn] = __builtin_amdgcn_mfma_f32_16x16x32_bf16(
                        af[0][fm], bg[0][fn], acc[fm][fn], 0, 0, 0);
                    acc[fm][fn] = __builtin_amdgcn_mfma_f32_16x16x32_bf16(
                        af[0][fm], bg[1][fn], acc[fm][fn], 0, 0, 0);
                    acc[fm][fn] = __builtin_amdgcn_mfma_f32_16x16x32_bf16(
                        af[1][fm], bg[0][fn], acc[fm][fn], 0, 0, 0);
                    acc[fm][fn] = __builtin_amdgcn_mfma_f32_16x16x32_bf16(
                        af[1][fm], bg[1][fn], acc[fm][fn], 0, 0, 0);
                    acc[fm][fn] = __builtin_amdgcn_mfma_f32_16x16x32_bf16(
                        af[0][fm], bg[2][fn], acc[fm][fn], 0, 0, 0);
                    acc[fm][fn] = __builtin_amdgcn_mfma_f32_16x16x32_bf16(
                        af[2][fm], bg[0][fn], acc[fm][fn], 0, 0, 0);
                }
        }
    }

    const int col = lane & 15, rq = lane >> 4;
    #pragma unroll
    for (int fm = 0; fm < 2; ++fm)
        #pragma unroll
        for (int fn = 0; fn < 2; ++fn) {
            const int nn = n0 + wn + fn * 16 + col;
            const float bv = bias[nn];
            #pragma unroll
            for (int r = 0; r < 4; ++r) {
                const int mm = m0 + wm + fm * 16 + rq * 4 + r;
                Y[mm * HH + nn] = acc[fm][fn][r] + bv;
            }
        }
}

// ---------------------------------------------------------------------------
__device__ inline unsigned f2key(float f) {
    unsigned u = __float_as_uint(f);
    return u ^ ((u & 0x80000000u) ? 0xFFFFFFFFu : 0x80000000u);
}

// ---------------------------------------------------------------------------
// span_scores v3: 32x32 (s,e) tiles, 2x2 register blocking, k-chunked LDS
// (42.5 KB -> 3 blocks/CU). LDS b128 reads per pair: 384 -> 160.
// Accumulation order per pair identical to R8 (absmax 0 preserved).
// ---------------------------------------------------------------------------
__global__ __launch_bounds__(256) void span_scores(
    const float* __restrict__ hs, const float* __restrict__ he,
    const float* __restrict__ w_score, const float* __restrict__ b_score,
    const int* __restrict__ input_mask, float* __restrict__ scores,
    unsigned* __restrict__ hist12)
{
    const int bx = blockIdx.x;
    const int b = bx / NT32;
    int tI = bx - b * NT32;
    int i = 0, cum = 0;
    while (tI >= cum + (8 - i)) { cum += 8 - i; ++i; }
    const int j = i + (tI - cum);
    const int s0 = i * 32, e0 = j * 32;

    __shared__ __align__(16) float shs[32][132];
    __shared__ __align__(16) float she[32][132];
    __shared__ __align__(16) float swc[128];
    __shared__ unsigned lh[2048];    // 4096 bins packed 2 x u16

    const int tid = threadIdx.x;
    const float4* hs4 = (const float4*)hs;
    const float4* he4 = (const float4*)he;

    for (int idx = tid; idx < 2048; idx += 256) lh[idx] = 0;

    const int ii = tid >> 4, jj = tid & 15;

    float4 acc[2][2];
    #pragma unroll
    for (int p = 0; p < 2; ++p)
        #pragma unroll
        for (int q = 0; q < 2; ++q) acc[p][q] = make_float4(0.f, 0.f, 0.f, 0.f);

    for (int ck = 0; ck < 4; ++ck) {
        const int kc = ck * 128;       // chunk base (floats)
        __syncthreads();               // prev-iter reads done
        #pragma unroll
        for (int l = 0; l < 4; ++l) {
            const int idx = l * 256 + tid;       // 0..1023
            const int row = idx >> 5, c4 = idx & 31;
            *(float4*)&shs[row][c4 * 4] =
                hs4[((b*TT + s0 + row) * HH + kc) / 4 + c4];
            *(float4*)&she[row][c4 * 4] =
                he4[((b*TT + e0 + row) * HH + kc) / 4 + c4];
        }
        if (tid < 32) *(float4*)&swc[tid * 4] =
            ((const float4*)w_score)[kc / 4 + tid];
        __syncthreads();

        #pragma unroll 4
        for (int c4 = 0; c4 < 32; ++c4) {
            const float4 w  = *(const float4*)&swc[c4 * 4];
            const float4 a0 = *(const float4*)&shs[ii][c4 * 4];
            const float4 a1 = *(const float4*)&shs[ii + 16][c4 * 4];
            const float4 v0 = *(const float4*)&she[jj][c4 * 4];
            const float4 v1 = *(const float4*)&she[jj + 16][c4 * 4];
            #pragma unroll
            for (int p = 0; p < 2; ++p) {
                const float4 a = p ? a1 : a0;
                #pragma unroll
                for (int q = 0; q < 2; ++q) {
                    const float4 v = q ? v1 : v0;
                    acc[p][q].x += fmaxf(a.x + v.x, 0.f) * w.x;
                    acc[p][q].y += fmaxf(a.y + v.y, 0.f) * w.y;
                    acc[p][q].z += fmaxf(a.z + v.z, 0.f) * w.z;
                    acc[p][q].w += fmaxf(a.w + v.w, 0.f) * w.w;
                }
            }
        }
    }

    const float bsc = b_score[0];
    #pragma unroll
    for (int p = 0; p < 2; ++p) {
        const int s = s0 + ii + p * 16;
        #pragma unroll
        for (int q = 0; q < 2; ++q) {
            const int e = e0 + jj + q * 16;
            if (e >= s) {
                const float4 a4 = acc[p][q];
                float scv = (a4.x + a4.y) + (a4.z + a4.w) + bsc;
                if (!(input_mask[b*TT + s] && input_mask[b*TT + e])) scv = NEGV;
                scores[b*NSPANS + s*TT - (s*(s-1))/2 + (e - s)] = scv;
                const unsigned bin = f2key(scv) >> 20;
                atomicAdd(&lh[bin >> 1], 1u << ((bin & 1u) * 16));
            }
        }
    }
    __syncthreads();

    for (int idx = tid; idx < 2048; idx += 256) {
        const unsigned w = lh[idx];
        const unsigned lo = w & 0xFFFFu, hi = w >> 16;
        if (lo) atomicAdd(&hist12[b*4096 + 2*idx],     lo);
        if (hi) atomicAdd(&hist12[b*4096 + 2*idx + 1], hi);
    }
}

// ---------------------------------------------------------------------------
__global__ __launch_bounds__(1024) void find12(
    const unsigned* __restrict__ hist12, unsigned* __restrict__ thrInfo)
{
    const int b = blockIdx.x;
    const unsigned* h = hist12 + b*4096;
    const int tid = threadIdx.x;
    const int lane = tid & 63, wave = tid >> 6;

    const int hi = 4095 - tid*4;
    unsigned psum = h[hi] + h[hi-1] + h[hi-2] + h[hi-3];

    unsigned inc = psum;
    #pragma unroll
    for (int off = 1; off < 64; off <<= 1) {
        unsigned n = __shfl_up(inc, off);
        if (lane >= off) inc += n;
    }
    __shared__ unsigned wsum[16], wpre[16];
    if (lane == 63) wsum[wave] = inc;
    __syncthreads();
    if (tid == 0) { unsigned c = 0; for (int w = 0; w < 16; ++w) { wpre[w] = c; c += wsum[w]; } }
    __syncthreads();

    const unsigned before = wpre[wave] + inc - psum;
    if (before < KK && before + psum >= KK && psum > 0) {
        unsigned cum = before;
        int bin = hi;
        for (int jj = 0; jj < 4; ++jj) {
            const unsigned c = h[hi - jj];
            if (cum + c >= KK) { bin = hi - jj; break; }
            cum += c;
        }
        thrInfo[b*4 + 0] = (unsigned)bin;
        thrInfo[b*4 + 1] = KK - cum;
    }
}

// ---------------------------------------------------------------------------
__global__ __launch_bounds__(256) void compact_cand(
    const float* __restrict__ scores, const unsigned* __restrict__ thrInfo,
    unsigned* __restrict__ cand, unsigned* __restrict__ candCnt)
{
    const int b = blockIdx.x >> 5, ch = blockIdx.x & 31;
    const float* sc = scores + b*NSPANS;
    const unsigned p12 = thrInfo[b*4 + 0];
    const int base = ch*CHSZ;
    for (int i = base + threadIdx.x; i < base + CHSZ; i += 256) {
        const unsigned key = f2key(sc[i]);
        if ((key >> 20) == p12) {
            const unsigned pos = atomicAdd(&candCnt[b], 1u);
            cand[b*NSPANS + pos] = key & 0xFFFFFu;
        }
    }
}

// ---------------------------------------------------------------------------
__global__ __launch_bounds__(1024) void refine(
    const unsigned* __restrict__ cand, const unsigned* __restrict__ candCnt,
    const float* __restrict__ scores,
    unsigned* __restrict__ thrInfo, unsigned* __restrict__ chunkBase)
{
    const int b = blockIdx.x;
    const unsigned* cd = cand + b*NSPANS;
    const unsigned n = candCnt[b];
    const unsigned remaining = thrInfo[b*4 + 1];
    const int tid = threadIdx.x;
    const int lane = tid & 63, wave = tid >> 6;

    __shared__ unsigned hist[1024];
    __shared__ unsigned wsum[16], wpre[16];
    __shared__ unsigned sh[2], shT[2];

    hist[tid] = 0;
    __syncthreads();
    for (unsigned i = tid; i < n; i += 1024) atomicAdd(&hist[(cd[i] >> 10) & 1023u], 1u);
    __syncthreads();
    {
        const unsigned psum = hist[1023 - tid];
        unsigned inc = psum;
        #pragma unroll
        for (int off = 1; off < 64; off <<= 1) {
            unsigned v = __shfl_up(inc, off);
            if (lane >= off) inc += v;
        }
        if (lane == 63) wsum[wave] = inc;
        __syncthreads();
        if (tid == 0) { unsigned c = 0; for (int w = 0; w < 16; ++w) { wpre[w] = c; c += wsum[w]; } }
        __syncthreads();
        const unsigned before = wpre[wave] + inc - psum;
        if (before < remaining && before + psum >= remaining && psum > 0) {
            sh[0] = 1023u - (unsigned)tid;
            sh[1] = remaining - before;
        }
        __syncthreads();
    }
    const unsigned b1 = sh[0], rem1 = sh[1];
    __syncthreads();

    hist[tid] = 0;
    __syncthreads();
    for (unsigned i = tid; i < n; i += 1024) {
        const unsigned v = cd[i];
        if (((v >> 10) & 1023u) == b1) atomicAdd(&hist[v & 1023u], 1u);
    }
    __syncthreads();
    {
        const unsigned psum = hist[1023 - tid];
        unsigned inc = psum;
        #pragma unroll
        for (int off = 1; off < 64; off <<= 1) {
            unsigned v = __shfl_up(inc, off);
            if (lane >= off) inc += v;
        }
        if (lane == 63) wsum[wave] = inc;
        __syncthreads();
        if (tid == 0) { unsigned c = 0; for (int w = 0; w < 16; ++w) { wpre[w] = c; c += wsum[w]; } }
        __syncthreads();
        const unsigned before = wpre[wave] + inc - psum;
        if (before < rem1 && before + psum >= rem1 && psum > 0) {
            const unsigned thrv = (thrInfo[b*4 + 0] << 20) | (b1 << 10) | (1023u - (unsigned)tid);
            thrInfo[b*4 + 2] = thrv;
            thrInfo[b*4 + 3] = rem1 - before;
            shT[0] = thrv;
            shT[1] = rem1 - before;
        }
    }
    __syncthreads();
    const unsigned thr = shT[0], ties = shT[1];

    __shared__ unsigned cg[NCH], ce[NCH];
    const float* sc = scores + b*NSPANS;
    #pragma unroll
    for (int q = 0; q < 2; ++q) {
        const int ch = wave*2 + q;
        const int base = ch*CHSZ, end = base + CHSZ;
        unsigned g = 0, e = 0;
        for (int i = base + lane; i < end; i += 64) {
            const unsigned key = f2key(sc[i]);
            g += (key > thr); e += (key == thr);
        }
        #pragma unroll
        for (int off = 32; off; off >>= 1) { g += __shfl_down(g, off); e += __shfl_down(e, off); }
        if (lane == 0) { cg[ch] = g; ce[ch] = e; }
    }
    __syncthreads();

    if (tid == 0) {
        unsigned out = 0, eqp = 0;
        for (int c = 0; c < NCH; ++c) {
            chunkBase[(b*NCH + c)*2 + 0] = out;
            chunkBase[(b*NCH + c)*2 + 1] = eqp;
            const unsigned room = (eqp >= ties) ? 0u : (ties - eqp);
            const unsigned taken = (ce[c] < room) ? ce[c] : room;
            out += cg[c] + taken;
            eqp += ce[c];
        }
    }
}

// ---------------------------------------------------------------------------
__global__ __launch_bounds__(256) void scatter(
    const float* __restrict__ scores, const unsigned* __restrict__ thrInfo,
    const unsigned* __restrict__ chunkBase, int* __restrict__ top_idx)
{
    const int b = blockIdx.x >> 5, ch = blockIdx.x & 31;
    const float* sc = scores + b*NSPANS;
    const unsigned thr = thrInfo[b*4 + 2], ties = thrInfo[b*4 + 3];
    unsigned outPos = chunkBase[(b*NCH + ch)*2 + 0];
    unsigned eqPos  = chunkBase[(b*NCH + ch)*2 + 1];

    const int tid = threadIdx.x, wave = tid >> 6, lane = tid & 63;
    const unsigned long long lmask = (1ull << lane) - 1ull;
    __shared__ unsigned wS[4], wE[4];

    const int base = ch*CHSZ;
    for (int seg = base; seg < base + CHSZ; seg += 256) {
        const int i = seg + tid;
        const bool valid = (i < base + CHSZ);
        const unsigned key = valid ? f2key(sc[i]) : 0u;
        const bool g  = valid && key > thr;
        const bool eq = valid && key == thr;

        const unsigned long long meq = __ballot(eq);
        if (lane == 0) wE[wave] = (unsigned)__popcll(meq);
        __syncthreads();

        unsigned eqPre = eqPos;
        for (int w = 0; w < wave; ++w) eqPre += wE[w];
        const unsigned myEqRank = eqPre + (unsigned)__popcll(meq & lmask);
        const bool sel = g || (eq && myEqRank < ties);

        const unsigned long long msel = __ballot(sel);
        if (lane == 0) wS[wave] = (unsigned)__popcll(msel);
        __syncthreads();

        unsigned selPre = outPos;
        for (int w = 0; w < wave; ++w) selPre += wS[w];
        if (sel) top_idx[b*KK + selPre + (unsigned)__popcll(msel & lmask)] = i;

        unsigned totS = 0, totE = 0;
        #pragma unroll
        for (int w = 0; w < 4; ++w) { totS += wS[w]; totE += wE[w]; }
        __syncthreads();
        outPos += totS; eqPos += totE;
    }
}

// ---------------------------------------------------------------------------
__global__ __launch_bounds__(1024) void finalize(
    const float* __restrict__ scores, const int* __restrict__ top_idx,
    const int* __restrict__ answer_spans, float* __restrict__ out)
{
    __shared__ int gold[BB*10];
    __shared__ float part[16];
    const int tid = threadIdx.x;

    if (tid < BB*10) {
        const int s0 = answer_spans[tid*2];
        const int e0 = answer_spans[tid*2 + 1];
        gold[tid] = (s0 >= 0) ? ((2*s0*TT - s0*s0 + s0)/2 + (e0 - s0)) : -1;
    }
    __syncthreads();

    float lsum = 0.f;
    for (int t = tid; t < BB*KK; t += 1024) {
        const int b = t >> 9;
        const int idx = top_idx[t];
        const float l = scores[b*NSPANS + idx];
        float prob = 0.f;
        if (l > -1e19f) {
            prob = 1.f / (1.f + expf(-l));
            float pred = 0.f;
            #pragma unroll
            for (int g = 0; g < 10; ++g)
                if (gold[b*10 + g] == idx) pred = 1.f;
            lsum += fmaxf(l, 0.f) - l*pred + log1pf(expf(-fabsf(l)));
        }
        out[t] = prob;
    }

    #pragma unroll
    for (int off = 32; off; off >>= 1) lsum += __shfl_down(lsum, off);
    const int wave = tid >> 6, lane = tid & 63;
    if (lane == 0) part[wave] = lsum;
    __syncthreads();
    if (tid == 0) {
        float ssum = 0.f;
        for (int w = 0; w < 16; ++w) ssum += part[w];
        out[BB*KK] = ssum;
    }
}

// ---------------------------------------------------------------------------
extern "C" void kernel_launch(void* const* d_in, const int* in_sizes, int n_in,
                              void* d_out, int out_size, void* d_ws, size_t ws_size,
                              hipStream_t stream)
{
    const float* inputs       = (const float*)d_in[0];
    const int*   input_mask   = (const int*)  d_in[1];
    const int*   answer_spans = (const int*)  d_in[2];
    const float* W_start      = (const float*)d_in[3];
    const float* b_start      = (const float*)d_in[4];
    const float* W_end        = (const float*)d_in[5];
    const float* b_end        = (const float*)d_in[6];
    const float* w_score      = (const float*)d_in[7];
    const float* b_score      = (const float*)d_in[8];
    float* out = (float*)d_out;
    unsigned* ws = (unsigned*)d_ws;

    // word-offset layout
    float*    hs       = (float*)(ws);                 // 1048576
    float*    he       = (float*)(ws + 1048576);       // 1048576
    float*    scores   = (float*)(ws + 2097152);       // 263168
    int*      top_idx  = (int*)  (ws + 2360320);       // 4096
    unsigned* thrInfo  = ws + 2364416;                 // 32
    unsigned* chunkBase= ws + 2364448;                 // 512
    unsigned* hist12   = ws + 2364960;                 // 32768
    unsigned* candCnt  = ws + 2397728;                 // 8 (contiguous w/ hist12)
    unsigned short* xs = (unsigned short*)(ws + 2397736);   // 3*2097152 bf16
    unsigned short* wt = (unsigned short*)(ws + 5543464);   // 2*3*524288 bf16
    unsigned* cand     = (unsigned*)hs;                // alias, hs dead after span

    hipMemsetAsync(hist12, 0, (size_t)(BB*4096 + BB)*4, stream);  // hist12+candCnt

    cvt_x<<<2048, 256, 0, stream>>>(inputs, xs, xs + 2097152, xs + 4194304);
    cvt_w<<<4096, 256, 0, stream>>>(W_start, W_end, wt);
    gemm_mfma<<<512, 256, 0, stream>>>(xs, wt, b_start, b_end, hs, he);

    span_scores<<<BB*NT32, 256, 0, stream>>>(hs, he, w_score, b_score, input_mask,
                                             scores, hist12);

    find12      <<<BB, 1024, 0, stream>>>(hist12, thrInfo);
    compact_cand<<<BB*NCH, 256, 0, stream>>>(scores, thrInfo, cand, candCnt);
    refine      <<<BB, 1024, 0, stream>>>(cand, candCnt, scores, thrInfo, chunkBase);
    scatter     <<<BB*NCH, 256, 0, stream>>>(scores, thrInfo, chunkBase, top_idx);

    finalize<<<1, 1024, 0, stream>>>(scores, top_idx, answer_spans, out);
}

// Round 10
// 122.815 us; speedup vs baseline: 1.9044x; 1.0049x over previous
//
#include <hip/hip_runtime.h>
#include <hip/hip_bf16.h>
#include <math.h>

#define BB 8
#define TT 256
#define DD 1024
#define HH 512
#define NSPANS 32896   // T*(T+1)/2
#define KK 512
#define NEGV -1e20f
#define NCH 32
#define CHSZ 1028      // NSPANS / NCH
#define NT32 36        // 8*9/2 span tiles (32x32) per batch

typedef __attribute__((ext_vector_type(8))) short bf16x8;
typedef __attribute__((ext_vector_type(4))) float f32x4;

__device__ inline unsigned short f2bf(float f) {          // RNE f32->bf16
    unsigned u = __float_as_uint(f);
    return (unsigned short)((u + 0x7FFFu + ((u >> 16) & 1u)) >> 16);
}
__device__ inline float bf2f(unsigned short u) {
    return __uint_as_float(((unsigned)u) << 16);
}
__device__ inline void split3(float v, unsigned short& a, unsigned short& b,
                              unsigned short& c) {
    a = f2bf(v);           float r  = v - bf2f(a);
    b = f2bf(r);           float r2 = r - bf2f(b);
    c = f2bf(r2);
}

// ---------------------------------------------------------------------------
// zero_hist: zero hist12 (32768 words) + candCnt (8 words), contiguous.
// Replaces hipMemsetAsync whose rocclr fill kernel cost ~43 us in-graph (R9).
// ---------------------------------------------------------------------------
__global__ __launch_bounds__(256) void zero_hist(unsigned* __restrict__ p)
{
    const int stride = gridDim.x * 256;
    for (int i = blockIdx.x * 256 + threadIdx.x; i < 32776; i += stride)
        p[i] = 0u;
}

// ---------------------------------------------------------------------------
// cvt_x: X [2048][1024] f32 -> xs0/1/2 bf16 (same layout). 4 elems/thread.
// ---------------------------------------------------------------------------
__global__ __launch_bounds__(256) void cvt_x(
    const float* __restrict__ X, unsigned short* __restrict__ x0,
    unsigned short* __restrict__ x1, unsigned short* __restrict__ x2)
{
    const int i4 = blockIdx.x * 256 + threadIdx.x;     // float4 index
    const float4 v = ((const float4*)X)[i4];
    const float vv[4] = {v.x, v.y, v.z, v.w};
    ushort4 h0, h1, h2;
    unsigned short* p0 = (unsigned short*)&h0;
    unsigned short* p1 = (unsigned short*)&h1;
    unsigned short* p2 = (unsigned short*)&h2;
    #pragma unroll
    for (int j = 0; j < 4; ++j) split3(vv[j], p0[j], p1[j], p2[j]);
    ((ushort4*)x0)[i4] = h0;
    ((ushort4*)x1)[i4] = h1;
    ((ushort4*)x2)[i4] = h2;
}

// ---------------------------------------------------------------------------
// cvt_w: Ws/We [1024][512] f32 -> wt [2][3][512][1024] bf16, TRANSPOSED.
// ---------------------------------------------------------------------------
__global__ __launch_bounds__(256) void cvt_w(
    const float* __restrict__ Ws, const float* __restrict__ We,
    unsigned short* __restrict__ wt)
{
    const int idx = blockIdx.x * 256 + threadIdx.x;    // 0 .. 2*524288
    const int z = idx >> 19;
    const int p = idx & 524287;                        // h*1024 + d
    const int h = p >> 10, d = p & 1023;
    const float v = (z ? We : Ws)[d * HH + h];
    unsigned short a, b, c;
    split3(v, a, b, c);
    unsigned short* base = wt + (size_t)z * 3 * 524288;
    base[0 * 524288 + p] = a;
    base[1 * 524288 + p] = b;
    base[2 * 524288 + p] = c;
}

// ---------------------------------------------------------------------------
// gemm_mfma: hs = X@Ws + bs ; he = X@We + be via bf16x3 split, 6 products.
// 64x64 C-tile, 4 waves x (32x32), K-tile 64, mfma_f32_16x16x32_bf16.
// ---------------------------------------------------------------------------
__global__ __launch_bounds__(256) void gemm_mfma(
    const unsigned short* __restrict__ xs,   // [3][2048][1024]
    const unsigned short* __restrict__ wt,   // [2][3][512][1024] (n-major)
    const float* __restrict__ bs, const float* __restrict__ be,
    float* __restrict__ hs, float* __restrict__ he)
{
    const int bid = blockIdx.x;
    const int lg  = ((bid & 7) << 6) + (bid >> 3);   // XCD-chunked swizzle
    const int z   = lg >> 8;
    const int my  = (lg & 255) >> 3, nx = lg & 7;
    const int m0 = my * 64, n0 = nx * 64;

    const unsigned short* __restrict__ W = wt + (size_t)z * 3 * 524288;
    const float* __restrict__ bias = z ? be : bs;
    float* __restrict__ Y = z ? he : hs;

    __shared__ __align__(16) unsigned short la[3][64][72];
    __shared__ __align__(16) unsigned short lb[3][64][72];

    const int tid = threadIdx.x;
    const int wave = tid >> 6, lane = tid & 63;
    const int wm = (wave >> 1) * 32, wn = (wave & 1) * 32;

    f32x4 acc[2][2];
    #pragma unroll
    for (int i = 0; i < 2; ++i)
        #pragma unroll
        for (int j = 0; j < 2; ++j) acc[i][j] = (f32x4){0.f, 0.f, 0.f, 0.f};

    const int rA = lane & 15;
    const int kq = lane >> 4;

    for (int kt = 0; kt < 16; ++kt) {
        const int k0 = kt * 64;
        __syncthreads();
        #pragma unroll
        for (int sp = 0; sp < 3; ++sp) {
            #pragma unroll
            for (int it = 0; it < 2; ++it) {
                const int idx = it * 256 + tid;
                const int row = idx >> 3, c8 = idx & 7;
                *(int4*)&la[sp][row][c8 * 8] =
                    *(const int4*)&xs[(size_t)sp * 2097152 + (m0 + row) * 1024 + k0 + c8 * 8];
                *(int4*)&lb[sp][row][c8 * 8] =
                    *(const int4*)&W[(size_t)sp * 524288 + (n0 + row) * 1024 + k0 + c8 * 8];
            }
        }
        __syncthreads();

        #pragma unroll
        for (int s = 0; s < 2; ++s) {
            const int kl = s * 32 + kq * 8;
            bf16x8 af[3][2], bg[3][2];
            #pragma unroll
            for (int sp = 0; sp < 3; ++sp) {
                #pragma unroll
                for (int f = 0; f < 2; ++f) {
                    af[sp][f] = *(const bf16x8*)&la[sp][wm + f * 16 + rA][kl];
                    bg[sp][f] = *(const bf16x8*)&lb[sp][wn + f * 16 + rA][kl];
                }
            }
            #pragma unroll
            for (int fm = 0; fm < 2; ++fm)
                #pragma unroll
                for (int fn = 0; fn < 2; ++fn) {
                    acc[fm][fn] = __builtin_amdgcn_mfma_f32_16x16x32_bf16(
                        af[0][fm], bg[0][fn], acc[fm][fn], 0, 0, 0);
                    acc[fm][fn] = __builtin_amdgcn_mfma_f32_16x16x32_bf16(
                        af[0][fm], bg[1][fn], acc[fm][fn], 0, 0, 0);
                    acc[fm][fn] = __builtin_amdgcn_mfma_f32_16x16x32_bf16(
                        af[1][fm], bg[0][fn], acc[fm][fn], 0, 0, 0);
                    acc[fm][fn] = __builtin_amdgcn_mfma_f32_16x16x32_bf16(
                        af[1][fm], bg[1][fn], acc[fm][fn], 0, 0, 0);
                    acc[fm][fn] = __builtin_amdgcn_mfma_f32_16x16x32_bf16(
                        af[0][fm], bg[2][fn], acc[fm][fn], 0, 0, 0);
                    acc[fm][fn] = __builtin_amdgcn_mfma_f32_16x16x32_bf16(
                        af[2][fm], bg[0][fn], acc[fm][fn], 0, 0, 0);
                }
        }
    }

    const int col = lane & 15, rq = lane >> 4;
    #pragma unroll
    for (int fm = 0; fm < 2; ++fm)
        #pragma unroll
        for (int fn = 0; fn < 2; ++fn) {
            const int nn = n0 + wn + fn * 16 + col;
            const float bv = bias[nn];
            #pragma unroll
            for (int r = 0; r < 4; ++r) {
                const int mm = m0 + wm + fm * 16 + rq * 4 + r;
                Y[mm * HH + nn] = acc[fm][fn][r] + bv;
            }
        }
}

// ---------------------------------------------------------------------------
__device__ inline unsigned f2key(float f) {
    unsigned u = __float_as_uint(f);
    return u ^ ((u & 0x80000000u) ? 0xFFFFFFFFu : 0x80000000u);
}

// ---------------------------------------------------------------------------
// span_scores v3: 32x32 (s,e) tiles, 2x2 register blocking, k-chunked LDS.
// ---------------------------------------------------------------------------
__global__ __launch_bounds__(256) void span_scores(
    const float* __restrict__ hs, const float* __restrict__ he,
    const float* __restrict__ w_score, const float* __restrict__ b_score,
    const int* __restrict__ input_mask, float* __restrict__ scores,
    unsigned* __restrict__ hist12)
{
    const int bx = blockIdx.x;
    const int b = bx / NT32;
    int tI = bx - b * NT32;
    int i = 0, cum = 0;
    while (tI >= cum + (8 - i)) { cum += 8 - i; ++i; }
    const int j = i + (tI - cum);
    const int s0 = i * 32, e0 = j * 32;

    __shared__ __align__(16) float shs[32][132];
    __shared__ __align__(16) float she[32][132];
    __shared__ __align__(16) float swc[128];
    __shared__ unsigned lh[2048];    // 4096 bins packed 2 x u16

    const int tid = threadIdx.x;
    const float4* hs4 = (const float4*)hs;
    const float4* he4 = (const float4*)he;

    for (int idx = tid; idx < 2048; idx += 256) lh[idx] = 0;

    const int ii = tid >> 4, jj = tid & 15;

    float4 acc[2][2];
    #pragma unroll
    for (int p = 0; p < 2; ++p)
        #pragma unroll
        for (int q = 0; q < 2; ++q) acc[p][q] = make_float4(0.f, 0.f, 0.f, 0.f);

    for (int ck = 0; ck < 4; ++ck) {
        const int kc = ck * 128;       // chunk base (floats)
        __syncthreads();               // prev-iter reads done
        #pragma unroll
        for (int l = 0; l < 4; ++l) {
            const int idx = l * 256 + tid;       // 0..1023
            const int row = idx >> 5, c4 = idx & 31;
            *(float4*)&shs[row][c4 * 4] =
                hs4[((b*TT + s0 + row) * HH + kc) / 4 + c4];
            *(float4*)&she[row][c4 * 4] =
                he4[((b*TT + e0 + row) * HH + kc) / 4 + c4];
        }
        if (tid < 32) *(float4*)&swc[tid * 4] =
            ((const float4*)w_score)[kc / 4 + tid];
        __syncthreads();

        #pragma unroll 4
        for (int c4 = 0; c4 < 32; ++c4) {
            const float4 w  = *(const float4*)&swc[c4 * 4];
            const float4 a0 = *(const float4*)&shs[ii][c4 * 4];
            const float4 a1 = *(const float4*)&shs[ii + 16][c4 * 4];
            const float4 v0 = *(const float4*)&she[jj][c4 * 4];
            const float4 v1 = *(const float4*)&she[jj + 16][c4 * 4];
            #pragma unroll
            for (int p = 0; p < 2; ++p) {
                const float4 a = p ? a1 : a0;
                #pragma unroll
                for (int q = 0; q < 2; ++q) {
                    const float4 v = q ? v1 : v0;
                    acc[p][q].x += fmaxf(a.x + v.x, 0.f) * w.x;
                    acc[p][q].y += fmaxf(a.y + v.y, 0.f) * w.y;
                    acc[p][q].z += fmaxf(a.z + v.z, 0.f) * w.z;
                    acc[p][q].w += fmaxf(a.w + v.w, 0.f) * w.w;
                }
            }
        }
    }

    const float bsc = b_score[0];
    #pragma unroll
    for (int p = 0; p < 2; ++p) {
        const int s = s0 + ii + p * 16;
        #pragma unroll
        for (int q = 0; q < 2; ++q) {
            const int e = e0 + jj + q * 16;
            if (e >= s) {
                const float4 a4 = acc[p][q];
                float scv = (a4.x + a4.y) + (a4.z + a4.w) + bsc;
                if (!(input_mask[b*TT + s] && input_mask[b*TT + e])) scv = NEGV;
                scores[b*NSPANS + s*TT - (s*(s-1))/2 + (e - s)] = scv;
                const unsigned bin = f2key(scv) >> 20;
                atomicAdd(&lh[bin >> 1], 1u << ((bin & 1u) * 16));
            }
        }
    }
    __syncthreads();

    for (int idx = tid; idx < 2048; idx += 256) {
        const unsigned w = lh[idx];
        const unsigned lo = w & 0xFFFFu, hi = w >> 16;
        if (lo) atomicAdd(&hist12[b*4096 + 2*idx],     lo);
        if (hi) atomicAdd(&hist12[b*4096 + 2*idx + 1], hi);
    }
}

// ---------------------------------------------------------------------------
__global__ __launch_bounds__(1024) void find12(
    const unsigned* __restrict__ hist12, unsigned* __restrict__ thrInfo)
{
    const int b = blockIdx.x;
    const unsigned* h = hist12 + b*4096;
    const int tid = threadIdx.x;
    const int lane = tid & 63, wave = tid >> 6;

    const int hi = 4095 - tid*4;
    unsigned psum = h[hi] + h[hi-1] + h[hi-2] + h[hi-3];

    unsigned inc = psum;
    #pragma unroll
    for (int off = 1; off < 64; off <<= 1) {
        unsigned n = __shfl_up(inc, off);
        if (lane >= off) inc += n;
    }
    __shared__ unsigned wsum[16], wpre[16];
    if (lane == 63) wsum[wave] = inc;
    __syncthreads();
    if (tid == 0) { unsigned c = 0; for (int w = 0; w < 16; ++w) { wpre[w] = c; c += wsum[w]; } }
    __syncthreads();

    const unsigned before = wpre[wave] + inc - psum;
    if (before < KK && before + psum >= KK && psum > 0) {
        unsigned cum = before;
        int bin = hi;
        for (int jj = 0; jj < 4; ++jj) {
            const unsigned c = h[hi - jj];
            if (cum + c >= KK) { bin = hi - jj; break; }
            cum += c;
        }
        thrInfo[b*4 + 0] = (unsigned)bin;
        thrInfo[b*4 + 1] = KK - cum;
    }
}

// ---------------------------------------------------------------------------
__global__ __launch_bounds__(256) void compact_cand(
    const float* __restrict__ scores, const unsigned* __restrict__ thrInfo,
    unsigned* __restrict__ cand, unsigned* __restrict__ candCnt)
{
    const int b = blockIdx.x >> 5, ch = blockIdx.x & 31;
    const float* sc = scores + b*NSPANS;
    const unsigned p12 = thrInfo[b*4 + 0];
    const int base = ch*CHSZ;
    for (int i = base + threadIdx.x; i < base + CHSZ; i += 256) {
        const unsigned key = f2key(sc[i]);
        if ((key >> 20) == p12) {
            const unsigned pos = atomicAdd(&candCnt[b], 1u);
            cand[b*NSPANS + pos] = key & 0xFFFFFu;
        }
    }
}

// ---------------------------------------------------------------------------
__global__ __launch_bounds__(1024) void refine(
    const unsigned* __restrict__ cand, const unsigned* __restrict__ candCnt,
    const float* __restrict__ scores,
    unsigned* __restrict__ thrInfo, unsigned* __restrict__ chunkBase)
{
    const int b = blockIdx.x;
    const unsigned* cd = cand + b*NSPANS;
    const unsigned n = candCnt[b];
    const unsigned remaining = thrInfo[b*4 + 1];
    const int tid = threadIdx.x;
    const int lane = tid & 63, wave = tid >> 6;

    __shared__ unsigned hist[1024];
    __shared__ unsigned wsum[16], wpre[16];
    __shared__ unsigned sh[2], shT[2];

    hist[tid] = 0;
    __syncthreads();
    for (unsigned i = tid; i < n; i += 1024) atomicAdd(&hist[(cd[i] >> 10) & 1023u], 1u);
    __syncthreads();
    {
        const unsigned psum = hist[1023 - tid];
        unsigned inc = psum;
        #pragma unroll
        for (int off = 1; off < 64; off <<= 1) {
            unsigned v = __shfl_up(inc, off);
            if (lane >= off) inc += v;
        }
        if (lane == 63) wsum[wave] = inc;
        __syncthreads();
        if (tid == 0) { unsigned c = 0; for (int w = 0; w < 16; ++w) { wpre[w] = c; c += wsum[w]; } }
        __syncthreads();
        const unsigned before = wpre[wave] + inc - psum;
        if (before < remaining && before + psum >= remaining && psum > 0) {
            sh[0] = 1023u - (unsigned)tid;
            sh[1] = remaining - before;
        }
        __syncthreads();
    }
    const unsigned b1 = sh[0], rem1 = sh[1];
    __syncthreads();

    hist[tid] = 0;
    __syncthreads();
    for (unsigned i = tid; i < n; i += 1024) {
        const unsigned v = cd[i];
        if (((v >> 10) & 1023u) == b1) atomicAdd(&hist[v & 1023u], 1u);
    }
    __syncthreads();
    {
        const unsigned psum = hist[1023 - tid];
        unsigned inc = psum;
        #pragma unroll
        for (int off = 1; off < 64; off <<= 1) {
            unsigned v = __shfl_up(inc, off);
            if (lane >= off) inc += v;
        }
        if (lane == 63) wsum[wave] = inc;
        __syncthreads();
        if (tid == 0) { unsigned c = 0; for (int w = 0; w < 16; ++w) { wpre[w] = c; c += wsum[w]; } }
        __syncthreads();
        const unsigned before = wpre[wave] + inc - psum;
        if (before < rem1 && before + psum >= rem1 && psum > 0) {
            const unsigned thrv = (thrInfo[b*4 + 0] << 20) | (b1 << 10) | (1023u - (unsigned)tid);
            thrInfo[b*4 + 2] = thrv;
            thrInfo[b*4 + 3] = rem1 - before;
            shT[0] = thrv;
            shT[1] = rem1 - before;
        }
    }
    __syncthreads();
    const unsigned thr = shT[0], ties = shT[1];

    __shared__ unsigned cg[NCH], ce[NCH];
    const float* sc = scores + b*NSPANS;
    #pragma unroll
    for (int q = 0; q < 2; ++q) {
        const int ch = wave*2 + q;
        const int base = ch*CHSZ, end = base + CHSZ;
        unsigned g = 0, e = 0;
        for (int i = base + lane; i < end; i += 64) {
            const unsigned key = f2key(sc[i]);
            g += (key > thr); e += (key == thr);
        }
        #pragma unroll
        for (int off = 32; off; off >>= 1) { g += __shfl_down(g, off); e += __shfl_down(e, off); }
        if (lane == 0) { cg[ch] = g; ce[ch] = e; }
    }
    __syncthreads();

    if (tid == 0) {
        unsigned out = 0, eqp = 0;
        for (int c = 0; c < NCH; ++c) {
            chunkBase[(b*NCH + c)*2 + 0] = out;
            chunkBase[(b*NCH + c)*2 + 1] = eqp;
            const unsigned room = (eqp >= ties) ? 0u : (ties - eqp);
            const unsigned taken = (ce[c] < room) ? ce[c] : room;
            out += cg[c] + taken;
            eqp += ce[c];
        }
    }
}

// ---------------------------------------------------------------------------
__global__ __launch_bounds__(256) void scatter(
    const float* __restrict__ scores, const unsigned* __restrict__ thrInfo,
    const unsigned* __restrict__ chunkBase, int* __restrict__ top_idx)
{
    const int b = blockIdx.x >> 5, ch = blockIdx.x & 31;
    const float* sc = scores + b*NSPANS;
    const unsigned thr = thrInfo[b*4 + 2], ties = thrInfo[b*4 + 3];
    unsigned outPos = chunkBase[(b*NCH + ch)*2 + 0];
    unsigned eqPos  = chunkBase[(b*NCH + ch)*2 + 1];

    const int tid = threadIdx.x, wave = tid >> 6, lane = tid & 63;
    const unsigned long long lmask = (1ull << lane) - 1ull;
    __shared__ unsigned wS[4], wE[4];

    const int base = ch*CHSZ;
    for (int seg = base; seg < base + CHSZ; seg += 256) {
        const int i = seg + tid;
        const bool valid = (i < base + CHSZ);
        const unsigned key = valid ? f2key(sc[i]) : 0u;
        const bool g  = valid && key > thr;
        const bool eq = valid && key == thr;

        const unsigned long long meq = __ballot(eq);
        if (lane == 0) wE[wave] = (unsigned)__popcll(meq);
        __syncthreads();

        unsigned eqPre = eqPos;
        for (int w = 0; w < wave; ++w) eqPre += wE[w];
        const unsigned myEqRank = eqPre + (unsigned)__popcll(meq & lmask);
        const bool sel = g || (eq && myEqRank < ties);

        const unsigned long long msel = __ballot(sel);
        if (lane == 0) wS[wave] = (unsigned)__popcll(msel);
        __syncthreads();

        unsigned selPre = outPos;
        for (int w = 0; w < wave; ++w) selPre += wS[w];
        if (sel) top_idx[b*KK + selPre + (unsigned)__popcll(msel & lmask)] = i;

        unsigned totS = 0, totE = 0;
        #pragma unroll
        for (int w = 0; w < 4; ++w) { totS += wS[w]; totE += wE[w]; }
        __syncthreads();
        outPos += totS; eqPos += totE;
    }
}

// ---------------------------------------------------------------------------
__global__ __launch_bounds__(1024) void finalize(
    const float* __restrict__ scores, const int* __restrict__ top_idx,
    const int* __restrict__ answer_spans, float* __restrict__ out)
{
    __shared__ int gold[BB*10];
    __shared__ float part[16];
    const int tid = threadIdx.x;

    if (tid < BB*10) {
        const int s0 = answer_spans[tid*2];
        const int e0 = answer_spans[tid*2 + 1];
        gold[tid] = (s0 >= 0) ? ((2*s0*TT - s0*s0 + s0)/2 + (e0 - s0)) : -1;
    }
    __syncthreads();

    float lsum = 0.f;
    for (int t = tid; t < BB*KK; t += 1024) {
        const int b = t >> 9;
        const int idx = top_idx[t];
        const float l = scores[b*NSPANS + idx];
        float prob = 0.f;
        if (l > -1e19f) {
            prob = 1.f / (1.f + expf(-l));
            float pred = 0.f;
            #pragma unroll
            for (int g = 0; g < 10; ++g)
                if (gold[b*10 + g] == idx) pred = 1.f;
            lsum += fmaxf(l, 0.f) - l*pred + log1pf(expf(-fabsf(l)));
        }
        out[t] = prob;
    }

    #pragma unroll
    for (int off = 32; off; off >>= 1) lsum += __shfl_down(lsum, off);
    const int wave = tid >> 6, lane = tid & 63;
    if (lane == 0) part[wave] = lsum;
    __syncthreads();
    if (tid == 0) {
        float ssum = 0.f;
        for (int w = 0; w < 16; ++w) ssum += part[w];
        out[BB*KK] = ssum;
    }
}

// ---------------------------------------------------------------------------
extern "C" void kernel_launch(void* const* d_in, const int* in_sizes, int n_in,
                              void* d_out, int out_size, void* d_ws, size_t ws_size,
                              hipStream_t stream)
{
    const float* inputs       = (const float*)d_in[0];
    const int*   input_mask   = (const int*)  d_in[1];
    const int*   answer_spans = (const int*)  d_in[2];
    const float* W_start      = (const float*)d_in[3];
    const float* b_start      = (const float*)d_in[4];
    const float* W_end        = (const float*)d_in[5];
    const float* b_end        = (const float*)d_in[6];
    const float* w_score      = (const float*)d_in[7];
    const float* b_score      = (const float*)d_in[8];
    float* out = (float*)d_out;
    unsigned* ws = (unsigned*)d_ws;

    // word-offset layout
    float*    hs       = (float*)(ws);                 // 1048576
    float*    he       = (float*)(ws + 1048576);       // 1048576
    float*    scores   = (float*)(ws + 2097152);       // 263168
    int*      top_idx  = (int*)  (ws + 2360320);       // 4096
    unsigned* thrInfo  = ws + 2364416;                 // 32
    unsigned* chunkBase= ws + 2364448;                 // 512
    unsigned* hist12   = ws + 2364960;                 // 32768
    unsigned* candCnt  = ws + 2397728;                 // 8 (contiguous w/ hist12)
    unsigned short* xs = (unsigned short*)(ws + 2397736);   // 3*2097152 bf16
    unsigned short* wt = (unsigned short*)(ws + 5543464);   // 2*3*524288 bf16
    unsigned* cand     = (unsigned*)hs;                // alias, hs dead after span

    zero_hist<<<32, 256, 0, stream>>>(hist12);   // hist12 + candCnt (contiguous)

    cvt_x<<<2048, 256, 0, stream>>>(inputs, xs, xs + 2097152, xs + 4194304);
    cvt_w<<<4096, 256, 0, stream>>>(W_start, W_end, wt);
    gemm_mfma<<<512, 256, 0, stream>>>(xs, wt, b_start, b_end, hs, he);

    span_scores<<<BB*NT32, 256, 0, stream>>>(hs, he, w_score, b_score, input_mask,
                                             scores, hist12);

    find12      <<<BB, 1024, 0, stream>>>(hist12, thrInfo);
    compact_cand<<<BB*NCH, 256, 0, stream>>>(scores, thrInfo, cand, candCnt);
    refine      <<<BB, 1024, 0, stream>>>(cand, candCnt, scores, thrInfo, chunkBase);
    scatter     <<<BB*NCH, 256, 0, stream>>>(scores, thrInfo, chunkBase, top_idx);

    finalize<<<1, 1024, 0, stream>>>(scores, top_idx, answer_spans, out);
}

// Round 11
// 114.768 us; speedup vs baseline: 2.0380x; 1.0701x over previous
//
#include <hip/hip_runtime.h>
#include <hip/hip_bf16.h>
#include <math.h>

#define BB 8
#define TT 256
#define DD 1024
#define HH 512
#define NSPANS 32896   // T*(T+1)/2
#define KK 512
#define NEGV -1e20f
#define NCH 32
#define CHSZ 1028      // NSPANS / NCH
#define NT32 36        // 8*9/2 span tiles (32x32) per batch

typedef __attribute__((ext_vector_type(8))) short bf16x8;
typedef __attribute__((ext_vector_type(4))) float f32x4;

__device__ inline unsigned short f2bf(float f) {          // RNE f32->bf16
    unsigned u = __float_as_uint(f);
    return (unsigned short)((u + 0x7FFFu + ((u >> 16) & 1u)) >> 16);
}
__device__ inline float bf2f(unsigned short u) {
    return __uint_as_float(((unsigned)u) << 16);
}
__device__ inline void split3(float v, unsigned short& a, unsigned short& b,
                              unsigned short& c) {
    a = f2bf(v);           float r  = v - bf2f(a);
    b = f2bf(r);           float r2 = r - bf2f(b);
    c = f2bf(r2);
}

// ---------------------------------------------------------------------------
// prep: fused zero_hist + cvt_x + cvt_w (independent work, disjoint outputs).
// blocks [0,2048)   : cvt_x  — X f32 -> 3x bf16 split arrays
// blocks [2048,6144): cvt_w  — W f32 -> 3x bf16 split, transposed [n][k]
// blocks [6144,6176): zero hist12+candCnt (32776 words)
// ---------------------------------------------------------------------------
__global__ __launch_bounds__(256) void prep(
    const float* __restrict__ X,
    const float* __restrict__ Ws, const float* __restrict__ We,
    unsigned short* __restrict__ x0, unsigned short* __restrict__ x1,
    unsigned short* __restrict__ x2, unsigned short* __restrict__ wt,
    unsigned* __restrict__ zp)
{
    const int blk = blockIdx.x;
    const int tid = threadIdx.x;

    if (blk < 2048) {                               // ---- cvt_x ----
        const int i4 = blk * 256 + tid;
        const float4 v = ((const float4*)X)[i4];
        const float vv[4] = {v.x, v.y, v.z, v.w};
        ushort4 h0, h1, h2;
        unsigned short* p0 = (unsigned short*)&h0;
        unsigned short* p1 = (unsigned short*)&h1;
        unsigned short* p2 = (unsigned short*)&h2;
        #pragma unroll
        for (int j = 0; j < 4; ++j) split3(vv[j], p0[j], p1[j], p2[j]);
        ((ushort4*)x0)[i4] = h0;
        ((ushort4*)x1)[i4] = h1;
        ((ushort4*)x2)[i4] = h2;
    } else if (blk < 6144) {                        // ---- cvt_w ----
        const int idx = (blk - 2048) * 256 + tid;   // 0 .. 2*524288
        const int z = idx >> 19;
        const int p = idx & 524287;                 // h*1024 + d
        const int h = p >> 10, d = p & 1023;
        const float v = (z ? We : Ws)[d * HH + h];
        unsigned short a, b, c;
        split3(v, a, b, c);
        unsigned short* base = wt + (size_t)z * 3 * 524288;
        base[0 * 524288 + p] = a;
        base[1 * 524288 + p] = b;
        base[2 * 524288 + p] = c;
    } else {                                        // ---- zero ----
        const int i = (blk - 6144) * 256 + tid;
        for (int k = i; k < 32776; k += 32 * 256) zp[k] = 0u;
    }
}

// ---------------------------------------------------------------------------
// gemm_mfma: hs = X@Ws + bs ; he = X@We + be via bf16x3 split, 6 products.
// 64x64 C-tile, 4 waves x (32x32), K-tile 64, mfma_f32_16x16x32_bf16.
// ---------------------------------------------------------------------------
__global__ __launch_bounds__(256) void gemm_mfma(
    const unsigned short* __restrict__ xs,   // [3][2048][1024]
    const unsigned short* __restrict__ wt,   // [2][3][512][1024] (n-major)
    const float* __restrict__ bs, const float* __restrict__ be,
    float* __restrict__ hs, float* __restrict__ he)
{
    const int bid = blockIdx.x;
    const int lg  = ((bid & 7) << 6) + (bid >> 3);   // XCD-chunked swizzle
    const int z   = lg >> 8;
    const int my  = (lg & 255) >> 3, nx = lg & 7;
    const int m0 = my * 64, n0 = nx * 64;

    const unsigned short* __restrict__ W = wt + (size_t)z * 3 * 524288;
    const float* __restrict__ bias = z ? be : bs;
    float* __restrict__ Y = z ? he : hs;

    __shared__ __align__(16) unsigned short la[3][64][72];
    __shared__ __align__(16) unsigned short lb[3][64][72];

    const int tid = threadIdx.x;
    const int wave = tid >> 6, lane = tid & 63;
    const int wm = (wave >> 1) * 32, wn = (wave & 1) * 32;

    f32x4 acc[2][2];
    #pragma unroll
    for (int i = 0; i < 2; ++i)
        #pragma unroll
        for (int j = 0; j < 2; ++j) acc[i][j] = (f32x4){0.f, 0.f, 0.f, 0.f};

    const int rA = lane & 15;
    const int kq = lane >> 4;

    for (int kt = 0; kt < 16; ++kt) {
        const int k0 = kt * 64;
        __syncthreads();
        #pragma unroll
        for (int sp = 0; sp < 3; ++sp) {
            #pragma unroll
            for (int it = 0; it < 2; ++it) {
                const int idx = it * 256 + tid;
                const int row = idx >> 3, c8 = idx & 7;
                *(int4*)&la[sp][row][c8 * 8] =
                    *(const int4*)&xs[(size_t)sp * 2097152 + (m0 + row) * 1024 + k0 + c8 * 8];
                *(int4*)&lb[sp][row][c8 * 8] =
                    *(const int4*)&W[(size_t)sp * 524288 + (n0 + row) * 1024 + k0 + c8 * 8];
            }
        }
        __syncthreads();

        #pragma unroll
        for (int s = 0; s < 2; ++s) {
            const int kl = s * 32 + kq * 8;
            bf16x8 af[3][2], bg[3][2];
            #pragma unroll
            for (int sp = 0; sp < 3; ++sp) {
                #pragma unroll
                for (int f = 0; f < 2; ++f) {
                    af[sp][f] = *(const bf16x8*)&la[sp][wm + f * 16 + rA][kl];
                    bg[sp][f] = *(const bf16x8*)&lb[sp][wn + f * 16 + rA][kl];
                }
            }
            #pragma unroll
            for (int fm = 0; fm < 2; ++fm)
                #pragma unroll
                for (int fn = 0; fn < 2; ++fn) {
                    acc[fm][fn] = __builtin_amdgcn_mfma_f32_16x16x32_bf16(
                        af[0][fm], bg[0][fn], acc[fm][fn], 0, 0, 0);
                    acc[fm][fn] = __builtin_amdgcn_mfma_f32_16x16x32_bf16(
                        af[0][fm], bg[1][fn], acc[fm][fn], 0, 0, 0);
                    acc[fm][fn] = __builtin_amdgcn_mfma_f32_16x16x32_bf16(
                        af[1][fm], bg[0][fn], acc[fm][fn], 0, 0, 0);
                    acc[fm][fn] = __builtin_amdgcn_mfma_f32_16x16x32_bf16(
                        af[1][fm], bg[1][fn], acc[fm][fn], 0, 0, 0);
                    acc[fm][fn] = __builtin_amdgcn_mfma_f32_16x16x32_bf16(
                        af[0][fm], bg[2][fn], acc[fm][fn], 0, 0, 0);
                    acc[fm][fn] = __builtin_amdgcn_mfma_f32_16x16x32_bf16(
                        af[2][fm], bg[0][fn], acc[fm][fn], 0, 0, 0);
                }
        }
    }

    const int col = lane & 15, rq = lane >> 4;
    #pragma unroll
    for (int fm = 0; fm < 2; ++fm)
        #pragma unroll
        for (int fn = 0; fn < 2; ++fn) {
            const int nn = n0 + wn + fn * 16 + col;
            const float bv = bias[nn];
            #pragma unroll
            for (int r = 0; r < 4; ++r) {
                const int mm = m0 + wm + fm * 16 + rq * 4 + r;
                Y[mm * HH + nn] = acc[fm][fn][r] + bv;
            }
        }
}

// ---------------------------------------------------------------------------
__device__ inline unsigned f2key(float f) {
    unsigned u = __float_as_uint(f);
    return u ^ ((u & 0x80000000u) ? 0xFFFFFFFFu : 0x80000000u);
}

// ---------------------------------------------------------------------------
// span_scores v3: 32x32 (s,e) tiles, 2x2 register blocking, k-chunked LDS.
// ---------------------------------------------------------------------------
__global__ __launch_bounds__(256) void span_scores(
    const float* __restrict__ hs, const float* __restrict__ he,
    const float* __restrict__ w_score, const float* __restrict__ b_score,
    const int* __restrict__ input_mask, float* __restrict__ scores,
    unsigned* __restrict__ hist12)
{
    const int bx = blockIdx.x;
    const int b = bx / NT32;
    int tI = bx - b * NT32;
    int i = 0, cum = 0;
    while (tI >= cum + (8 - i)) { cum += 8 - i; ++i; }
    const int j = i + (tI - cum);
    const int s0 = i * 32, e0 = j * 32;

    __shared__ __align__(16) float shs[32][132];
    __shared__ __align__(16) float she[32][132];
    __shared__ __align__(16) float swc[128];
    __shared__ unsigned lh[2048];    // 4096 bins packed 2 x u16

    const int tid = threadIdx.x;
    const float4* hs4 = (const float4*)hs;
    const float4* he4 = (const float4*)he;

    for (int idx = tid; idx < 2048; idx += 256) lh[idx] = 0;

    const int ii = tid >> 4, jj = tid & 15;

    float4 acc[2][2];
    #pragma unroll
    for (int p = 0; p < 2; ++p)
        #pragma unroll
        for (int q = 0; q < 2; ++q) acc[p][q] = make_float4(0.f, 0.f, 0.f, 0.f);

    for (int ck = 0; ck < 4; ++ck) {
        const int kc = ck * 128;       // chunk base (floats)
        __syncthreads();               // prev-iter reads done
        #pragma unroll
        for (int l = 0; l < 4; ++l) {
            const int idx = l * 256 + tid;       // 0..1023
            const int row = idx >> 5, c4 = idx & 31;
            *(float4*)&shs[row][c4 * 4] =
                hs4[((b*TT + s0 + row) * HH + kc) / 4 + c4];
            *(float4*)&she[row][c4 * 4] =
                he4[((b*TT + e0 + row) * HH + kc) / 4 + c4];
        }
        if (tid < 32) *(float4*)&swc[tid * 4] =
            ((const float4*)w_score)[kc / 4 + tid];
        __syncthreads();

        #pragma unroll 4
        for (int c4 = 0; c4 < 32; ++c4) {
            const float4 w  = *(const float4*)&swc[c4 * 4];
            const float4 a0 = *(const float4*)&shs[ii][c4 * 4];
            const float4 a1 = *(const float4*)&shs[ii + 16][c4 * 4];
            const float4 v0 = *(const float4*)&she[jj][c4 * 4];
            const float4 v1 = *(const float4*)&she[jj + 16][c4 * 4];
            #pragma unroll
            for (int p = 0; p < 2; ++p) {
                const float4 a = p ? a1 : a0;
                #pragma unroll
                for (int q = 0; q < 2; ++q) {
                    const float4 v = q ? v1 : v0;
                    acc[p][q].x += fmaxf(a.x + v.x, 0.f) * w.x;
                    acc[p][q].y += fmaxf(a.y + v.y, 0.f) * w.y;
                    acc[p][q].z += fmaxf(a.z + v.z, 0.f) * w.z;
                    acc[p][q].w += fmaxf(a.w + v.w, 0.f) * w.w;
                }
            }
        }
    }

    const float bsc = b_score[0];
    #pragma unroll
    for (int p = 0; p < 2; ++p) {
        const int s = s0 + ii + p * 16;
        #pragma unroll
        for (int q = 0; q < 2; ++q) {
            const int e = e0 + jj + q * 16;
            if (e >= s) {
                const float4 a4 = acc[p][q];
                float scv = (a4.x + a4.y) + (a4.z + a4.w) + bsc;
                if (!(input_mask[b*TT + s] && input_mask[b*TT + e])) scv = NEGV;
                scores[b*NSPANS + s*TT - (s*(s-1))/2 + (e - s)] = scv;
                const unsigned bin = f2key(scv) >> 20;
                atomicAdd(&lh[bin >> 1], 1u << ((bin & 1u) * 16));
            }
        }
    }
    __syncthreads();

    for (int idx = tid; idx < 2048; idx += 256) {
        const unsigned w = lh[idx];
        const unsigned lo = w & 0xFFFFu, hi = w >> 16;
        if (lo) atomicAdd(&hist12[b*4096 + 2*idx],     lo);
        if (hi) atomicAdd(&hist12[b*4096 + 2*idx + 1], hi);
    }
}

// ---------------------------------------------------------------------------
// findcompact: per-block re-derivation of the 12-bit prefix (16 bins/thread,
// descending, 4-wave block scan) + compaction of this block's chunk.
// Replaces find12 + compact_cand. thrInfo[0..1] written idempotently.
// ---------------------------------------------------------------------------
__global__ __launch_bounds__(256) void findcompact(
    const float* __restrict__ scores, const unsigned* __restrict__ hist12,
    unsigned* __restrict__ thrInfo,
    unsigned* __restrict__ cand, unsigned* __restrict__ candCnt)
{
    const int b = blockIdx.x >> 5, ch = blockIdx.x & 31;
    const unsigned* h = hist12 + b * 4096;
    const int tid = threadIdx.x;
    const int lane = tid & 63, wave = tid >> 6;

    // ---- find12 scan: thread t owns bins [4095-16t .. 4080-16t] ----
    const int topbin = 4095 - tid * 16;
    unsigned psum = 0;
    #pragma unroll
    for (int j = 0; j < 16; ++j) psum += h[topbin - j];

    unsigned inc = psum;
    #pragma unroll
    for (int off = 1; off < 64; off <<= 1) {
        unsigned v = __shfl_up(inc, off);
        if (lane >= off) inc += v;
    }
    __shared__ unsigned wsum4[4], wpre4[4];
    __shared__ unsigned shp[2];
    if (lane == 63) wsum4[wave] = inc;
    __syncthreads();
    if (tid == 0) { unsigned c = 0; for (int w = 0; w < 4; ++w) { wpre4[w] = c; c += wsum4[w]; } }
    __syncthreads();

    const unsigned before = wpre4[wave] + inc - psum;
    if (before < KK && before + psum >= KK) {
        unsigned cum = before;
        int bin = topbin;
        #pragma unroll
        for (int j = 0; j < 16; ++j) {
            const unsigned c = h[topbin - j];
            if (cum + c >= KK) { bin = topbin - j; break; }
            cum += c;
        }
        shp[0] = (unsigned)bin;
        shp[1] = KK - cum;
        thrInfo[b*4 + 0] = (unsigned)bin;   // idempotent across blocks
        thrInfo[b*4 + 1] = KK - cum;
    }
    __syncthreads();
    const unsigned p12 = shp[0];

    // ---- compact this chunk ----
    const float* sc = scores + b * NSPANS;
    const int base = ch * CHSZ;
    for (int i = base + tid; i < base + CHSZ; i += 256) {
        const unsigned key = f2key(sc[i]);
        if ((key >> 20) == p12) {
            const unsigned pos = atomicAdd(&candCnt[b], 1u);
            cand[b*NSPANS + pos] = key & 0xFFFFFu;
        }
    }
}

// ---------------------------------------------------------------------------
__global__ __launch_bounds__(1024) void refine(
    const unsigned* __restrict__ cand, const unsigned* __restrict__ candCnt,
    const float* __restrict__ scores,
    unsigned* __restrict__ thrInfo, unsigned* __restrict__ chunkBase)
{
    const int b = blockIdx.x;
    const unsigned* cd = cand + b*NSPANS;
    const unsigned n = candCnt[b];
    const unsigned remaining = thrInfo[b*4 + 1];
    const int tid = threadIdx.x;
    const int lane = tid & 63, wave = tid >> 6;

    __shared__ unsigned hist[1024];
    __shared__ unsigned wsum[16], wpre[16];
    __shared__ unsigned sh[2], shT[2];

    hist[tid] = 0;
    __syncthreads();
    for (unsigned i = tid; i < n; i += 1024) atomicAdd(&hist[(cd[i] >> 10) & 1023u], 1u);
    __syncthreads();
    {
        const unsigned psum = hist[1023 - tid];
        unsigned inc = psum;
        #pragma unroll
        for (int off = 1; off < 64; off <<= 1) {
            unsigned v = __shfl_up(inc, off);
            if (lane >= off) inc += v;
        }
        if (lane == 63) wsum[wave] = inc;
        __syncthreads();
        if (tid == 0) { unsigned c = 0; for (int w = 0; w < 16; ++w) { wpre[w] = c; c += wsum[w]; } }
        __syncthreads();
        const unsigned before = wpre[wave] + inc - psum;
        if (before < remaining && before + psum >= remaining && psum > 0) {
            sh[0] = 1023u - (unsigned)tid;
            sh[1] = remaining - before;
        }
        __syncthreads();
    }
    const unsigned b1 = sh[0], rem1 = sh[1];
    __syncthreads();

    hist[tid] = 0;
    __syncthreads();
    for (unsigned i = tid; i < n; i += 1024) {
        const unsigned v = cd[i];
        if (((v >> 10) & 1023u) == b1) atomicAdd(&hist[v & 1023u], 1u);
    }
    __syncthreads();
    {
        const unsigned psum = hist[1023 - tid];
        unsigned inc = psum;
        #pragma unroll
        for (int off = 1; off < 64; off <<= 1) {
            unsigned v = __shfl_up(inc, off);
            if (lane >= off) inc += v;
        }
        if (lane == 63) wsum[wave] = inc;
        __syncthreads();
        if (tid == 0) { unsigned c = 0; for (int w = 0; w < 16; ++w) { wpre[w] = c; c += wsum[w]; } }
        __syncthreads();
        const unsigned before = wpre[wave] + inc - psum;
        if (before < rem1 && before + psum >= rem1 && psum > 0) {
            const unsigned thrv = (thrInfo[b*4 + 0] << 20) | (b1 << 10) | (1023u - (unsigned)tid);
            thrInfo[b*4 + 2] = thrv;
            thrInfo[b*4 + 3] = rem1 - before;
            shT[0] = thrv;
            shT[1] = rem1 - before;
        }
    }
    __syncthreads();
    const unsigned thr = shT[0], ties = shT[1];

    __shared__ unsigned cg[NCH], ce[NCH];
    const float* sc = scores + b*NSPANS;
    #pragma unroll
    for (int q = 0; q < 2; ++q) {
        const int ch = wave*2 + q;
        const int base = ch*CHSZ, end = base + CHSZ;
        unsigned g = 0, e = 0;
        for (int i = base + lane; i < end; i += 64) {
            const unsigned key = f2key(sc[i]);
            g += (key > thr); e += (key == thr);
        }
        #pragma unroll
        for (int off = 32; off; off >>= 1) { g += __shfl_down(g, off); e += __shfl_down(e, off); }
        if (lane == 0) { cg[ch] = g; ce[ch] = e; }
    }
    __syncthreads();

    if (tid == 0) {
        unsigned out = 0, eqp = 0;
        for (int c = 0; c < NCH; ++c) {
            chunkBase[(b*NCH + c)*2 + 0] = out;
            chunkBase[(b*NCH + c)*2 + 1] = eqp;
            const unsigned room = (eqp >= ties) ? 0u : (ties - eqp);
            const unsigned taken = (ce[c] < room) ? ce[c] : room;
            out += cg[c] + taken;
            eqp += ce[c];
        }
    }
}

// ---------------------------------------------------------------------------
__global__ __launch_bounds__(256) void scatter(
    const float* __restrict__ scores, const unsigned* __restrict__ thrInfo,
    const unsigned* __restrict__ chunkBase, int* __restrict__ top_idx)
{
    const int b = blockIdx.x >> 5, ch = blockIdx.x & 31;
    const float* sc = scores + b*NSPANS;
    const unsigned thr = thrInfo[b*4 + 2], ties = thrInfo[b*4 + 3];
    unsigned outPos = chunkBase[(b*NCH + ch)*2 + 0];
    unsigned eqPos  = chunkBase[(b*NCH + ch)*2 + 1];

    const int tid = threadIdx.x, wave = tid >> 6, lane = tid & 63;
    const unsigned long long lmask = (1ull << lane) - 1ull;
    __shared__ unsigned wS[4], wE[4];

    const int base = ch*CHSZ;
    for (int seg = base; seg < base + CHSZ; seg += 256) {
        const int i = seg + tid;
        const bool valid = (i < base + CHSZ);
        const unsigned key = valid ? f2key(sc[i]) : 0u;
        const bool g  = valid && key > thr;
        const bool eq = valid && key == thr;

        const unsigned long long meq = __ballot(eq);
        if (lane == 0) wE[wave] = (unsigned)__popcll(meq);
        __syncthreads();

        unsigned eqPre = eqPos;
        for (int w = 0; w < wave; ++w) eqPre += wE[w];
        const unsigned myEqRank = eqPre + (unsigned)__popcll(meq & lmask);
        const bool sel = g || (eq && myEqRank < ties);

        const unsigned long long msel = __ballot(sel);
        if (lane == 0) wS[wave] = (unsigned)__popcll(msel);
        __syncthreads();

        unsigned selPre = outPos;
        for (int w = 0; w < wave; ++w) selPre += wS[w];
        if (sel) top_idx[b*KK + selPre + (unsigned)__popcll(msel & lmask)] = i;

        unsigned totS = 0, totE = 0;
        #pragma unroll
        for (int w = 0; w < 4; ++w) { totS += wS[w]; totE += wE[w]; }
        __syncthreads();
        outPos += totS; eqPos += totE;
    }
}

// ---------------------------------------------------------------------------
__global__ __launch_bounds__(1024) void finalize(
    const float* __restrict__ scores, const int* __restrict__ top_idx,
    const int* __restrict__ answer_spans, float* __restrict__ out)
{
    __shared__ int gold[BB*10];
    __shared__ float part[16];
    const int tid = threadIdx.x;

    if (tid < BB*10) {
        const int s0 = answer_spans[tid*2];
        const int e0 = answer_spans[tid*2 + 1];
        gold[tid] = (s0 >= 0) ? ((2*s0*TT - s0*s0 + s0)/2 + (e0 - s0)) : -1;
    }
    __syncthreads();

    float lsum = 0.f;
    for (int t = tid; t < BB*KK; t += 1024) {
        const int b = t >> 9;
        const int idx = top_idx[t];
        const float l = scores[b*NSPANS + idx];
        float prob = 0.f;
        if (l > -1e19f) {
            prob = 1.f / (1.f + expf(-l));
            float pred = 0.f;
            #pragma unroll
            for (int g = 0; g < 10; ++g)
                if (gold[b*10 + g] == idx) pred = 1.f;
            lsum += fmaxf(l, 0.f) - l*pred + log1pf(expf(-fabsf(l)));
        }
        out[t] = prob;
    }

    #pragma unroll
    for (int off = 32; off; off >>= 1) lsum += __shfl_down(lsum, off);
    const int wave = tid >> 6, lane = tid & 63;
    if (lane == 0) part[wave] = lsum;
    __syncthreads();
    if (tid == 0) {
        float ssum = 0.f;
        for (int w = 0; w < 16; ++w) ssum += part[w];
        out[BB*KK] = ssum;
    }
}

// ---------------------------------------------------------------------------
extern "C" void kernel_launch(void* const* d_in, const int* in_sizes, int n_in,
                              void* d_out, int out_size, void* d_ws, size_t ws_size,
                              hipStream_t stream)
{
    const float* inputs       = (const float*)d_in[0];
    const int*   input_mask   = (const int*)  d_in[1];
    const int*   answer_spans = (const int*)  d_in[2];
    const float* W_start      = (const float*)d_in[3];
    const float* b_start      = (const float*)d_in[4];
    const float* W_end        = (const float*)d_in[5];
    const float* b_end        = (const float*)d_in[6];
    const float* w_score      = (const float*)d_in[7];
    const float* b_score      = (const float*)d_in[8];
    float* out = (float*)d_out;
    unsigned* ws = (unsigned*)d_ws;

    // word-offset layout
    float*    hs       = (float*)(ws);                 // 1048576
    float*    he       = (float*)(ws + 1048576);       // 1048576
    float*    scores   = (float*)(ws + 2097152);       // 263168
    int*      top_idx  = (int*)  (ws + 2360320);       // 4096
    unsigned* thrInfo  = ws + 2364416;                 // 32
    unsigned* chunkBase= ws + 2364448;                 // 512
    unsigned* hist12   = ws + 2364960;                 // 32768
    unsigned* candCnt  = ws + 2397728;                 // 8 (contiguous w/ hist12)
    unsigned short* xs = (unsigned short*)(ws + 2397736);   // 3*2097152 bf16
    unsigned short* wt = (unsigned short*)(ws + 5543464);   // 2*3*524288 bf16
    unsigned* cand     = (unsigned*)hs;                // alias, hs dead after span

    prep<<<6176, 256, 0, stream>>>(inputs, W_start, W_end,
                                   xs, xs + 2097152, xs + 4194304, wt, hist12);

    gemm_mfma<<<512, 256, 0, stream>>>(xs, wt, b_start, b_end, hs, he);

    span_scores<<<BB*NT32, 256, 0, stream>>>(hs, he, w_score, b_score, input_mask,
                                             scores, hist12);

    findcompact<<<BB*NCH, 256, 0, stream>>>(scores, hist12, thrInfo, cand, candCnt);
    refine     <<<BB, 1024, 0, stream>>>(cand, candCnt, scores, thrInfo, chunkBase);
    scatter    <<<BB*NCH, 256, 0, stream>>>(scores, thrInfo, chunkBase, top_idx);

    finalize<<<1, 1024, 0, stream>>>(scores, top_idx, answer_spans, out);
}